// Round 7
// baseline (1314.303 us; speedup 1.0000x reference)
//
#include <hip/hip_runtime.h>

typedef __attribute__((ext_vector_type(8))) __bf16 bf16x8;
typedef __attribute__((ext_vector_type(4))) float f32x4;
typedef __attribute__((ext_vector_type(2))) float f32x2;

#define BB 2
#define TT 8
#define CC 64
#define HH 160
#define WW 160
#define HWW 25600
#define RR 16
#define C2 128
#define C4 256
#define C8 512
#define NSTEP 7
#define CHW (CC*HWW)
#define EPSV 1e-5f

__device__ __forceinline__ f32x4 mfma16(bf16x8 a, bf16x8 b, f32x4 c) {
    return __builtin_amdgcn_mfma_f32_16x16x32_bf16(a, b, c, 0, 0, 0);
}

// unpack 2 bf16 (one dword) -> f32x2 and fma with packed weights (v_pk_fma_f32)
__device__ __forceinline__ void bpk_fma(unsigned d, f32x2 w, f32x2& a) {
    f32x2 u;
    u.x = __uint_as_float(d << 16);
    u.y = __uint_as_float(d & 0xffff0000u);
    a = __builtin_elementwise_fma(u, w, a);
}

// ---------------- pool: mean over H,W for frames 0..6 (fp32 planar input) ----------------
__global__ void pool_kernel(const float* __restrict__ feat, float* __restrict__ pool) {
    int idx = blockIdx.x;                 // b*NSTEP*CC + f*CC + c
    int b = idx / (NSTEP * CC);
    int f = (idx / CC) % NSTEP;
    int c = idx % CC;
    const float4* src = (const float4*)(feat + ((size_t)(b * TT + f) * CC + c) * HWW);
    float s = 0.f;
    for (int i = threadIdx.x; i < HWW / 4; i += 256) {
        float4 v = src[i];
        s += v.x + v.y + v.z + v.w;
    }
    __shared__ float sm[256];
    sm[threadIdx.x] = s;
    __syncthreads();
    for (int off = 128; off > 0; off >>= 1) {
        if (threadIdx.x < off) sm[threadIdx.x] += sm[threadIdx.x + off];
        __syncthreads();
    }
    if (threadIdx.x == 0) pool[idx] = sm[0] * (1.0f / HWW);
}

// ---------------- dynamic depthwise weights -> wdT[bf][t][c] (fp32) ----------------
__global__ void wd_kernel(const float* __restrict__ pool, const float* __restrict__ w1,
                          const float* __restrict__ gamma, const float* __restrict__ beta,
                          const float* __restrict__ mean, const float* __restrict__ var,
                          const float* __restrict__ w2, const float* __restrict__ b2,
                          float* __restrict__ wdT) {
    int bf = blockIdx.x;                  // 0..BB*NSTEP-1
    __shared__ float z[RR];
    int tid = threadIdx.x;                // 64 threads
    if (tid < RR) {
        const float* p = pool + bf * CC;
        float s = 0.f;
        for (int c = 0; c < CC; c++) s += p[c] * w1[tid * CC + c];
        s = (s - mean[tid]) * rsqrtf(var[tid] + EPSV) * gamma[tid] + beta[tid];
        z[tid] = s > 0.f ? s : 0.f;
    }
    __syncthreads();
    for (int o = tid; o < CC * 9; o += 64) {
        float s = b2[o];
        #pragma unroll
        for (int r = 0; r < RR; r++) s += z[r] * w2[o * RR + r];
        int c = o / 9, t = o % 9;
        wdT[bf * 576 + t * CC + c] = s;
    }
}

// ---------------- copy init slice (t=7) fp32 planar into output ----------------
__global__ void copy_init_kernel(const float* __restrict__ feat, float* __restrict__ out) {
    int i = blockIdx.x * 256 + threadIdx.x;   // over BB*CHW/4
    int n4 = CHW / 4;
    int b = i / n4;
    int r = i % n4;
    size_t off = ((size_t)(b * TT + (TT - 1)) * CHW) / 4 + r;
    ((float4*)out)[off] = ((const float4*)feat)[off];
}

// ---------------- prep weights ----------------
// Bc1 now frag-packed: [ks][nt8][lane64][8], ks=t*4+kc, oc=nt*16+lm, ic=kc*32+lq*8+j
__global__ void prep_weights(const float* __restrict__ c1w,
                             const float* __restrict__ pi1, const float* __restrict__ pi2,
                             const float* __restrict__ po1, const float* __restrict__ po2,
                             const float* __restrict__ dw1, const float* __restrict__ dw2,
                             const float* __restrict__ dw1b, const float* __restrict__ dw2b,
                             __bf16* __restrict__ Bc1,
                             __bf16* __restrict__ Bpi1, __bf16* __restrict__ Bpi2,
                             __bf16* __restrict__ Bpo1, __bf16* __restrict__ Bpo2,
                             float* __restrict__ dwT12, float* __restrict__ dwb12,
                             __bf16* __restrict__ Bpk) {
    int idx = blockIdx.x * 256 + threadIdx.x;
    if (idx < 147456) {   // conv1 frag-packed
        int j = idx & 7, ln = (idx >> 3) & 63, nt = (idx >> 9) & 7, ks = idx >> 12;
        int lm = ln & 15, lq = ln >> 4;
        int oc = nt * 16 + lm;
        int t = ks >> 2, ic = (ks & 3) * 32 + lq * 8 + j;
        Bc1[idx] = (__bf16)c1w[(oc * 128 + ic) * 9 + t];
        return;
    }
    idx -= 147456;
    if (idx < 16384) { Bpi1[idx] = (__bf16)pi1[idx]; return; }
    idx -= 16384;
    if (idx < 16384) { Bpi2[idx] = (__bf16)pi2[idx]; return; }
    idx -= 16384;
    if (idx < 16384) { Bpo1[idx] = (__bf16)po1[idx]; return; }
    idx -= 16384;
    if (idx < 16384) { Bpo2[idx] = (__bf16)po2[idx]; return; }
    idx -= 16384;
    if (idx < 4608) {   // dwT12[t][c512]
        int t = idx / 512, c = idx % 512;
        dwT12[t * C8 + c] = (c < 256) ? dw1[c * 9 + t] : dw2[(c - 256) * 9 + t];
        return;
    }
    idx -= 4608;
    if (idx < 512) { dwb12[idx] = (idx < 256) ? dw1b[idx] : dw2b[idx - 256]; return; }
    idx -= 512;
    if (idx < 32768) {   // Bpk: po weights pre-packed in MFMA B-fragment order
        int j = idx & 7, ln = (idx >> 3) & 63, nt = (idx >> 9) & 3, kg = (idx >> 11) & 3, cc = idx >> 13;
        int lmx = ln & 15, lqx = ln >> 4;
        int oc = nt * 16 + lmx;
        int ci = (cc & 1) * 128 + kg * 32 + lqx * 8 + j;
        const float* src = (cc >> 1) ? po2 : po1;
        Bpk[idx] = (__bf16)src[oc * C4 + ci];
    }
}

// ---------------- feature planar fp32 -> pixel-major bf16 [bf][p][64] ----------------
__global__ void featPM_kernel(const float* __restrict__ feat, __bf16* __restrict__ featPM) {
    __shared__ float Lt[64 * 68];
    int bf = blockIdx.x / 400;            // b*TT+f, 0..15
    int p0 = (blockIdx.x % 400) * 64;
    int tid = threadIdx.x;
    int c = tid & 63, half = tid >> 6;
    const float* src = feat + ((size_t)bf * CC + c) * HWW + p0 + half * 16;
    #pragma unroll
    for (int k = 0; k < 16; k++) Lt[(half * 16 + k) * 68 + c] = src[k];
    __syncthreads();
    int cg = tid & 7;
    #pragma unroll
    for (int pass = 0; pass < 2; pass++) {
        int pl = (tid >> 3) + pass * 32;
        bf16x8 o;
        #pragma unroll
        for (int j = 0; j < 8; j++) o[j] = (__bf16)Lt[pl * 68 + cg * 8 + j];
        *(bf16x8*)(featPM + ((size_t)bf * HWW + p0 + pl) * CC + cg * 8) = o;
    }
}

// ---------------- dynamic depthwise conv: src (bf16 PM) -> fpPM (bf16 PM) ----------------
__global__ void dyndw_kernel(const __bf16* __restrict__ src, size_t bstr,
                             const float* __restrict__ wdT, const float* __restrict__ kc_bias,
                             __bf16* __restrict__ fpPM, int fx) {
    int gi = blockIdx.x * 256 + threadIdx.x;   // BB*HWW*8
    int c0 = (gi & 7) * 8;
    int rem = gi >> 3;
    int p = rem % HWW;
    int bb = rem / HWW;
    int py = p / WW, px = p % WW;
    float acc[8];
    float4 k0 = *(const float4*)(kc_bias + c0);
    float4 k1 = *(const float4*)(kc_bias + c0 + 4);
    acc[0]=k0.x; acc[1]=k0.y; acc[2]=k0.z; acc[3]=k0.w;
    acc[4]=k1.x; acc[5]=k1.y; acc[6]=k1.z; acc[7]=k1.w;
    const float* wb = wdT + (size_t)(bb * NSTEP + fx) * 576;
    const __bf16* sb = src + (size_t)bb * bstr;
    const int dyA[9] = {-1,-1,-1,0,0,0,1,1,1};
    const int dxA[9] = {-1,0,1,-1,0,1,-1,0,1};
    #pragma unroll
    for (int t = 0; t < 9; t++) {
        int dy = dyA[t], dx = dxA[t];
        if ((unsigned)(py + dy) < HH && (unsigned)(px + dx) < WW) {
            bf16x8 uv = *(const bf16x8*)(sb + (size_t)(p + dy * WW + dx) * CC + c0);
            float4 w0 = *(const float4*)(wb + t * CC + c0);
            float4 w1 = *(const float4*)(wb + t * CC + c0 + 4);
            acc[0] += (float)uv[0] * w0.x; acc[1] += (float)uv[1] * w0.y;
            acc[2] += (float)uv[2] * w0.z; acc[3] += (float)uv[3] * w0.w;
            acc[4] += (float)uv[4] * w1.x; acc[5] += (float)uv[5] * w1.y;
            acc[6] += (float)uv[6] * w1.z; acc[7] += (float)uv[7] * w1.w;
        }
    }
    bf16x8 o;
    #pragma unroll
    for (int j = 0; j < 8; j++) o[j] = (__bf16)acc[j];
    *(bf16x8*)(fpPM + ((size_t)bb * HWW + p) * CC + c0) = o;
}

// ---------------- conv1 implicit-GEMM: 8x16 px 2D tile, LDS A-halo, B-frags from global ----------------
// grid BB*200 (XCD-swizzled). Stage uA[10][18][128ch(+pad)] once; 36-K-step loop barrier-free.
__global__ void conv1_gemm(const __bf16* __restrict__ featPM, const __bf16* __restrict__ fpPM,
                           const __bf16* __restrict__ Bpkc, const float* __restrict__ bias,
                           __bf16* __restrict__ fusionPM, int fx) {
    __shared__ __align__(16) __bf16 uA[10 * 18 * 136];   // 48960 B
    const int tid = threadIdx.x;
    const int bid = blockIdx.x;
    const int wg = (bid & 7) * 50 + (bid >> 3);          // bijective XCD swizzle (400 % 8 == 0)
    const int bb = wg / 200;
    const int rem = wg % 200;
    const int r0 = (rem / 10) * 8, c0 = (rem % 10) * 16;
    const __bf16* featB = featPM + (size_t)(bb * TT + fx) * HWW * CC;
    const __bf16* fpB   = fpPM + (size_t)bb * HWW * CC;
    const int wv = tid >> 6, lane = tid & 63, lm = lane & 15, lq = lane >> 4;

    // ---- stage A-halo (zero-padded OOB): rows r0-1..r0+8, cols c0-1..c0+16 ----
    #pragma unroll
    for (int it = 0; it < 12; it++) {
        int idx = it * 256 + tid;                        // 2880 16B-chunks
        if (idx < 2880) {
            int s = idx >> 4, part = idx & 15;
            int r = s / 18, c = s % 18;
            int gr = r0 - 1 + r, gc = c0 - 1 + c;
            uint4 v = {0, 0, 0, 0};
            if ((unsigned)gr < HH && (unsigned)gc < WW) {
                const __bf16* sp = (part < 8)
                    ? featB + (size_t)(gr * WW + gc) * CC + part * 8
                    : fpB   + (size_t)(gr * WW + gc) * CC + (part - 8) * 8;
                v = *(const uint4*)sp;
            }
            *(uint4*)&uA[(r * 18 + c) * 136 + part * 8] = v;
        }
    }
    __syncthreads();

    f32x4 acc[2][8];
    #pragma unroll
    for (int mt = 0; mt < 2; mt++)
        #pragma unroll
        for (int nt = 0; nt < 8; nt++) acc[mt][nt] = (f32x4){0.f, 0.f, 0.f, 0.f};

    const __bf16* bp0 = Bpkc + (size_t)lane * 8;
    const int dyA[9] = {-1,-1,-1,0,0,0,1,1,1};
    const int dxA[9] = {-1,0,1,-1,0,1,-1,0,1};
    #pragma unroll
    for (int t = 0; t < 9; t++) {
        const int arow = wv * 2 + 1 + dyA[t];
        const int acol = lm + 1 + dxA[t];
        const int abase = (arow * 18 + acol) * 136;
        #pragma unroll
        for (int kc = 0; kc < 4; kc++) {
            const int ks = t * 4 + kc;
            bf16x8 af0 = *(const bf16x8*)&uA[abase + kc * 32 + lq * 8];
            bf16x8 af1 = *(const bf16x8*)&uA[abase + 18 * 136 + kc * 32 + lq * 8];
            const __bf16* bks = bp0 + (size_t)ks * 4096;
            #pragma unroll
            for (int nt = 0; nt < 8; nt++) {
                bf16x8 bfr = *(const bf16x8*)(bks + nt * 512);
                acc[0][nt] = mfma16(af0, bfr, acc[0][nt]);
                acc[1][nt] = mfma16(af1, bfr, acc[1][nt]);
            }
        }
    }
    __bf16* ob = fusionPM + (size_t)bb * HWW * C2;
    #pragma unroll
    for (int mt = 0; mt < 2; mt++) {
        const int prow = r0 + wv * 2 + mt;
        #pragma unroll
        for (int nt = 0; nt < 8; nt++) {
            const int oc = nt * 16 + lm;
            const float bs = bias[oc];
            #pragma unroll
            for (int r = 0; r < 4; r++) {
                const int pp = prow * WW + c0 + lq * 4 + r;
                float v = acc[mt][nt][r] + bs;
                v = v > 0.f ? v : 0.1f * v;
                ob[(size_t)pp * C2 + oc] = (__bf16)v;
            }
        }
    }
}

// ---------------- pw1 fused both branches: u12 = fusion_half @ pi^T + b (bf16 out) ----------------
// grid: BB * 200 * 4  (nb: branch = nb>>1, sub-half = nb&1)
__global__ void pw1_gemm(const __bf16* __restrict__ fusionPM,
                         const __bf16* __restrict__ Bpi1, const __bf16* __restrict__ Bpi2,
                         const float* __restrict__ pi1b, const float* __restrict__ pi2b,
                         __bf16* __restrict__ u12PM) {
    __shared__ __align__(16) __bf16 As[128 * 40];
    __shared__ __align__(16) __bf16 Bs[128 * 40];
    const int tid = threadIdx.x;
    const int bb = blockIdx.x / 800;
    const int rem = blockIdx.x % 800;
    const int p0 = (rem >> 2) * 128;
    const int nb = rem & 3;
    const int br = nb >> 1, ns = nb & 1;
    const __bf16* Bpi = br ? Bpi2 : Bpi1;
    const float* bias = br ? pi2b : pi1b;
    const int i = tid >> 1, h = tid & 1;
    const int p = p0 + i;
    const __bf16* fB = fusionPM + (size_t)bb * HWW * C2 + br * CC;
    const int wv = tid >> 6, lane = tid & 63, lm = lane & 15, lq = lane >> 4;
    f32x4 acc[2][8];
    #pragma unroll
    for (int mt = 0; mt < 2; mt++)
        #pragma unroll
        for (int nt = 0; nt < 8; nt++) acc[mt][nt] = (f32x4){0.f, 0.f, 0.f, 0.f};

    #pragma unroll
    for (int ks = 0; ks < 2; ks++) {
        const int ci0 = ks * 32;
        const __bf16* sp = fB + (size_t)p * C2 + ci0 + h * 16;
        uint4 a0 = *(const uint4*)(sp);
        uint4 a1 = *(const uint4*)(sp + 8);
        const __bf16* bp = Bpi + (size_t)(ns * 128 + i) * 64 + ci0 + h * 16;
        uint4 w0q = *(const uint4*)(bp);
        uint4 w1q = *(const uint4*)(bp + 8);
        __syncthreads();
        *(uint4*)&As[i * 40 + h * 16]     = a0;
        *(uint4*)&As[i * 40 + h * 16 + 8] = a1;
        *(uint4*)&Bs[i * 40 + h * 16]     = w0q;
        *(uint4*)&Bs[i * 40 + h * 16 + 8] = w1q;
        __syncthreads();
        bf16x8 af0 = *(const bf16x8*)&As[((wv * 2 + 0) * 16 + lm) * 40 + lq * 8];
        bf16x8 af1 = *(const bf16x8*)&As[((wv * 2 + 1) * 16 + lm) * 40 + lq * 8];
        #pragma unroll
        for (int nt = 0; nt < 8; nt++) {
            bf16x8 bf = *(const bf16x8*)&Bs[(nt * 16 + lm) * 40 + lq * 8];
            acc[0][nt] = mfma16(af0, bf, acc[0][nt]);
            acc[1][nt] = mfma16(af1, bf, acc[1][nt]);
        }
    }
    __bf16* ub = u12PM + (size_t)bb * HWW * C8;
    #pragma unroll
    for (int mt = 0; mt < 2; mt++) {
        #pragma unroll
        for (int nt = 0; nt < 8; nt++) {
            const int ocl = ns * 128 + nt * 16 + lm;      // within branch's 256
            const int oc = br * 256 + ocl;                // within 512
            const float bs = bias[ocl];
            #pragma unroll
            for (int r = 0; r < 4; r++) {
                const int pp = p0 + (wv * 2 + mt) * 16 + lq * 4 + r;
                ub[(size_t)pp * C8 + oc] = (__bf16)(acc[mt][nt][r] + bs);
            }
        }
    }
}

// ---------------- fused dw3x3 + pw2 + gate epilogue, 32-px tiles, LDS-staged u ----------------
// grid BB*800 (XCD-swizzled). Per chunk of 128 ch: stage u[3][34][128] -> LDS (OOB zero-filled),
// guard-free 9-tap dw via ds_read_b128 + v_pk_fma_f32, Vt -> MFMA vs frag-packed Bpk.
__global__ void dwpw2_gemm(const __bf16* __restrict__ u12PM,
                           const float* __restrict__ dwT12, const float* __restrict__ dwb12,
                           const __bf16* __restrict__ Bpk,
                           const float* __restrict__ pob1, const float* __restrict__ pob2,
                           const __bf16* __restrict__ fusionPM,
                           float* __restrict__ out, __bf16* __restrict__ outPM, int fx) {
    __shared__ __align__(16) __bf16 uL[3 * 34 * 128];   // 26112 B
    __shared__ __align__(16) __bf16 Vt[32 * 136];       //  8704 B
    const int tid = threadIdx.x;
    const int bid = blockIdx.x;
    const int wg = (bid & 7) * 200 + (bid >> 3);        // bijective XCD swizzle (1600 % 8 == 0)
    const int bb = wg / 800;
    const int p0 = (wg % 800) * 32;                     // strip: 32 px within one image row
    const int py = p0 / WW, px0 = p0 % WW;
    const __bf16* uB = u12PM + (size_t)bb * HWW * C8;
    const int wv = tid >> 6, lane = tid & 63, lm = lane & 15, lq = lane >> 4;
    const int mt = wv & 1, nh = wv >> 1;
    const int cg = tid & 15, prow = tid >> 4;           // ch-group 0..15, px 0..15 (+16)

    f32x4 acc[2][2];   // [branch][ntl]
    #pragma unroll
    for (int b = 0; b < 2; b++)
        #pragma unroll
        for (int n = 0; n < 2; n++) acc[b][n] = (f32x4){0.f, 0.f, 0.f, 0.f};

    const int rbase = py - 1, cbase = px0 - 1;

    #pragma unroll
    for (int cc = 0; cc < 4; cc++) {
        // ---- stage u chunk: rows py-1..py+1, cols px0-1..px0+32, ch [cc*128,+128) ----
        const int c0ch = cc * 128;
        #pragma unroll
        for (int it = 0; it < 7; it++) {
            int idx = it * 256 + tid;                   // 1632 16B-chunks
            if (idx < 1632) {
                int s = idx >> 4, part = idx & 15;
                int r = s / 34, c = s - r * 34;
                int gr = rbase + r, gc = cbase + c;
                uint4 v = {0,0,0,0};
                if ((unsigned)gr < HH && (unsigned)gc < WW)
                    v = *(const uint4*)(uB + (size_t)(gr * WW + gc) * C8 + c0ch + part * 8);
                *(uint4*)&uL[idx * 8] = v;
            }
        }
        __syncthreads();   // uL ready; also guarantees prev chunk's MFMA Vt-reads done

        // ---- dw 3x3: guard-free, packed fma ----
        const int c0 = c0ch + cg * 8;
        f32x2 a0[4], a1[4];
        {
            float4 b0 = *(const float4*)(dwb12 + c0);
            float4 b1 = *(const float4*)(dwb12 + c0 + 4);
            a0[0] = (f32x2){b0.x, b0.y}; a0[1] = (f32x2){b0.z, b0.w};
            a0[2] = (f32x2){b1.x, b1.y}; a0[3] = (f32x2){b1.z, b1.w};
            #pragma unroll
            for (int k = 0; k < 4; k++) a1[k] = a0[k];
        }
        #pragma unroll
        for (int t = 0; t < 9; t++) {
            const int dy = t / 3 - 1, dx = t % 3 - 1;
            float4 w0 = *(const float4*)(dwT12 + t * C8 + c0);
            float4 w1 = *(const float4*)(dwT12 + t * C8 + c0 + 4);
            f32x2 wp[4] = {(f32x2){w0.x, w0.y}, (f32x2){w0.z, w0.w},
                           (f32x2){w1.x, w1.y}, (f32x2){w1.z, w1.w}};
            const int base = ((1 + dy) * 34 + 1 + dx) * 128 + cg * 8;
            uint4 ua = *(const uint4*)&uL[base + prow * 128];
            uint4 ub4 = *(const uint4*)&uL[base + (prow + 16) * 128];
            bpk_fma(ua.x, wp[0], a0[0]); bpk_fma(ua.y, wp[1], a0[1]);
            bpk_fma(ua.z, wp[2], a0[2]); bpk_fma(ua.w, wp[3], a0[3]);
            bpk_fma(ub4.x, wp[0], a1[0]); bpk_fma(ub4.y, wp[1], a1[1]);
            bpk_fma(ub4.z, wp[2], a1[2]); bpk_fma(ub4.w, wp[3], a1[3]);
        }
        bf16x8 o0, o1;
        #pragma unroll
        for (int k = 0; k < 4; k++) {
            o0[2 * k] = (__bf16)a0[k].x; o0[2 * k + 1] = (__bf16)a0[k].y;
            o1[2 * k] = (__bf16)a1[k].x; o1[2 * k + 1] = (__bf16)a1[k].y;
        }
        *(bf16x8*)&Vt[prow * 136 + cg * 8]        = o0;
        *(bf16x8*)&Vt[(16 + prow) * 136 + cg * 8] = o1;
        __syncthreads();

        // ---- MFMA for this chunk's branch ----
        const int br = cc >> 1;
        const __bf16* bbase = Bpk + cc * 8192 + (size_t)lane * 8;
        #pragma unroll
        for (int kg = 0; kg < 4; kg++) {
            bf16x8 af = *(const bf16x8*)&Vt[(mt * 16 + lm) * 136 + kg * 32 + lq * 8];
            #pragma unroll
            for (int ntl = 0; ntl < 2; ntl++) {
                bf16x8 bfr = *(const bf16x8*)(bbase + kg * 2048 + (nh * 2 + ntl) * 512);
                acc[br][ntl] = mfma16(af, bfr, acc[br][ntl]);
            }
        }
    }
    // ---- epilogue: gate + combine ----
    const __bf16* fB = fusionPM + (size_t)bb * HWW * C2;
    __bf16* opB = outPM + (size_t)bb * HWW * CC;
    float* outp = out + (size_t)(bb * TT + fx) * CC * HWW;
    const int ppb = p0 + mt * 16 + lq * 4;
    #pragma unroll
    for (int ntl = 0; ntl < 2; ntl++) {
        const int oc = (nh * 2 + ntl) * 16 + lm;
        const float bs1 = pob1[oc];
        const float bs2 = pob2[oc];
        float4 vo;
        #pragma unroll
        for (int r = 0; r < 4; r++) {
            const int pp = ppb + r;
            float g1 = 1.f / (1.f + __expf(-(acc[0][ntl][r] + bs1)));
            float g2 = 1.f / (1.f + __expf(-(acc[1][ntl][r] + bs2)));
            float f1 = (float)fB[(size_t)pp * C2 + oc];
            float f2 = (float)fB[(size_t)pp * C2 + CC + oc];
            float val = f1 * g1 + f2 * g2;
            (&vo.x)[r] = val;
            opB[(size_t)pp * CC + oc] = (__bf16)val;
        }
        *(float4*)(outp + (size_t)oc * HWW + ppb) = vo;
    }
}

extern "C" void kernel_launch(void* const* d_in, const int* in_sizes, int n_in,
                              void* d_out, int out_size, void* d_ws, size_t ws_size,
                              hipStream_t stream) {
    const float* feat     = (const float*)d_in[0];
    const float* kc_w1    = (const float*)d_in[1];
    const float* kc_g     = (const float*)d_in[2];
    const float* kc_be    = (const float*)d_in[3];
    const float* kc_mu    = (const float*)d_in[4];
    const float* kc_var   = (const float*)d_in[5];
    const float* kc_w2    = (const float*)d_in[6];
    const float* kc_b2    = (const float*)d_in[7];
    const float* kc_bias  = (const float*)d_in[8];
    const float* conv1_w  = (const float*)d_in[9];
    const float* conv1_b  = (const float*)d_in[10];
    const float* pi1_w    = (const float*)d_in[11];
    const float* pi1_b    = (const float*)d_in[12];
    const float* dw1_w    = (const float*)d_in[13];
    const float* dw1_b    = (const float*)d_in[14];
    const float* po1_w    = (const float*)d_in[15];
    const float* po1_b    = (const float*)d_in[16];
    const float* pi2_w    = (const float*)d_in[17];
    const float* pi2_b    = (const float*)d_in[18];
    const float* dw2_w    = (const float*)d_in[19];
    const float* dw2_b    = (const float*)d_in[20];
    const float* po2_w    = (const float*)d_in[21];
    const float* po2_b    = (const float*)d_in[22];
    float* out = (float*)d_out;

    char* W = (char*)d_ws;
    __bf16* featPM   = (__bf16*)W; W += (size_t)BB * TT * HWW * CC * 2;   // 52.4 MB
    __bf16* fpPM     = (__bf16*)W; W += (size_t)BB * HWW * CC * 2;        //  6.6 MB
    __bf16* fusionPM = (__bf16*)W; W += (size_t)BB * HWW * C2 * 2;        // 13.1 MB
    __bf16* u12PM    = (__bf16*)W; W += (size_t)BB * HWW * C8 * 2;        // 52.4 MB (bf16)
    __bf16* outPM    = (__bf16*)W; W += (size_t)BB * HWW * CC * 2;        //  6.6 MB
    __bf16* Bc1      = (__bf16*)W; W += 294912;
    __bf16* Bpi1     = (__bf16*)W; W += 32768;
    __bf16* Bpi2     = (__bf16*)W; W += 32768;
    __bf16* Bpo1     = (__bf16*)W; W += 32768;
    __bf16* Bpo2     = (__bf16*)W; W += 32768;
    __bf16* Bpk      = (__bf16*)W; W += 65536;
    float*  dwT12    = (float*)W;  W += 18432;
    float*  dwb12    = (float*)W;  W += 2048;
    float*  poolb    = (float*)W;  W += 4096;
    float*  wdT      = (float*)W;  W += 32256;

    prep_weights<<<980, 256, 0, stream>>>(conv1_w, pi1_w, pi2_w, po1_w, po2_w, dw1_w, dw2_w,
                                          dw1_b, dw2_b,
                                          Bc1, Bpi1, Bpi2, Bpo1, Bpo2, dwT12, dwb12, Bpk);
    featPM_kernel<<<BB * TT * 400, 256, 0, stream>>>(feat, featPM);
    pool_kernel<<<BB * NSTEP * CC, 256, 0, stream>>>(feat, poolb);
    wd_kernel<<<BB * NSTEP, 64, 0, stream>>>(poolb, kc_w1, kc_g, kc_be, kc_mu, kc_var, kc_w2, kc_b2, wdT);
    copy_init_kernel<<<BB * CHW / 4 / 256, 256, 0, stream>>>(feat, out);

    for (int i = 0; i < NSTEP; i++) {
        int fx = NSTEP - 1 - i;   // 6..0
        const __bf16* src = (fx == NSTEP - 1) ? (featPM + (size_t)(TT - 1) * HWW * CC) : outPM;
        size_t bstr = (fx == NSTEP - 1) ? (size_t)TT * HWW * CC : (size_t)HWW * CC;
        dyndw_kernel<<<BB * HWW * 8 / 256, 256, 0, stream>>>(src, bstr, wdT, kc_bias, fpPM, fx);
        conv1_gemm<<<BB * 200, 256, 0, stream>>>(featPM, fpPM, Bc1, conv1_b, fusionPM, fx);
        pw1_gemm<<<BB * 800, 256, 0, stream>>>(fusionPM, Bpi1, Bpi2, pi1_b, pi2_b, u12PM);
        dwpw2_gemm<<<BB * 800, 256, 0, stream>>>(u12PM, dwT12, dwb12, Bpk, po1_b, po2_b, fusionPM, out, outPM, fx);
    }
}

// Round 9
// 1042.772 us; speedup vs baseline: 1.2604x; 1.2604x over previous
//
#include <hip/hip_runtime.h>

typedef __attribute__((ext_vector_type(8))) __bf16 bf16x8;
typedef __attribute__((ext_vector_type(4))) float f32x4;
typedef __attribute__((ext_vector_type(2))) float f32x2;

#define BB 2
#define TT 8
#define CC 64
#define HH 160
#define WW 160
#define HWW 25600
#define RR 16
#define C2 128
#define C4 256
#define C8 512
#define NSTEP 7
#define CHW (CC*HWW)
#define EPSV 1e-5f

__device__ __forceinline__ f32x4 mfma16(bf16x8 a, bf16x8 b, f32x4 c) {
    return __builtin_amdgcn_mfma_f32_16x16x32_bf16(a, b, c, 0, 0, 0);
}

// unpack 2 bf16 (one dword) -> f32x2 and fma with packed weights (v_pk_fma_f32)
__device__ __forceinline__ void bpk_fma(unsigned d, f32x2 w, f32x2& a) {
    f32x2 u;
    u.x = __uint_as_float(d << 16);
    u.y = __uint_as_float(d & 0xffff0000u);
    a = __builtin_elementwise_fma(u, w, a);
}

// ---------------- pool: mean over H,W for frames 0..6 (fp32 planar input) ----------------
__global__ void pool_kernel(const float* __restrict__ feat, float* __restrict__ pool) {
    int idx = blockIdx.x;                 // b*NSTEP*CC + f*CC + c
    int b = idx / (NSTEP * CC);
    int f = (idx / CC) % NSTEP;
    int c = idx % CC;
    const float4* src = (const float4*)(feat + ((size_t)(b * TT + f) * CC + c) * HWW);
    float s = 0.f;
    for (int i = threadIdx.x; i < HWW / 4; i += 256) {
        float4 v = src[i];
        s += v.x + v.y + v.z + v.w;
    }
    __shared__ float sm[256];
    sm[threadIdx.x] = s;
    __syncthreads();
    for (int off = 128; off > 0; off >>= 1) {
        if (threadIdx.x < off) sm[threadIdx.x] += sm[threadIdx.x + off];
        __syncthreads();
    }
    if (threadIdx.x == 0) pool[idx] = sm[0] * (1.0f / HWW);
}

// ---------------- dynamic depthwise weights -> wdT[bf][t][c] (fp32) ----------------
__global__ void wd_kernel(const float* __restrict__ pool, const float* __restrict__ w1,
                          const float* __restrict__ gamma, const float* __restrict__ beta,
                          const float* __restrict__ mean, const float* __restrict__ var,
                          const float* __restrict__ w2, const float* __restrict__ b2,
                          float* __restrict__ wdT) {
    int bf = blockIdx.x;                  // 0..BB*NSTEP-1
    __shared__ float z[RR];
    int tid = threadIdx.x;                // 64 threads
    if (tid < RR) {
        const float* p = pool + bf * CC;
        float s = 0.f;
        for (int c = 0; c < CC; c++) s += p[c] * w1[tid * CC + c];
        s = (s - mean[tid]) * rsqrtf(var[tid] + EPSV) * gamma[tid] + beta[tid];
        z[tid] = s > 0.f ? s : 0.f;
    }
    __syncthreads();
    for (int o = tid; o < CC * 9; o += 64) {
        float s = b2[o];
        #pragma unroll
        for (int r = 0; r < RR; r++) s += z[r] * w2[o * RR + r];
        int c = o / 9, t = o % 9;
        wdT[bf * 576 + t * CC + c] = s;
    }
}

// ---------------- copy init slice (t=7) fp32 planar into output ----------------
__global__ void copy_init_kernel(const float* __restrict__ feat, float* __restrict__ out) {
    int i = blockIdx.x * 256 + threadIdx.x;   // over BB*CHW/4
    int n4 = CHW / 4;
    int b = i / n4;
    int r = i % n4;
    size_t off = ((size_t)(b * TT + (TT - 1)) * CHW) / 4 + r;
    ((float4*)out)[off] = ((const float4*)feat)[off];
}

// ---------------- prep weights: Bc1 [oc][t*128+ic] (round-5 layout) + dw/po packs ----------------
__global__ void prep_weights(const float* __restrict__ c1w,
                             const float* __restrict__ pi1, const float* __restrict__ pi2,
                             const float* __restrict__ po1, const float* __restrict__ po2,
                             const float* __restrict__ dw1, const float* __restrict__ dw2,
                             const float* __restrict__ dw1b, const float* __restrict__ dw2b,
                             __bf16* __restrict__ Bc1,
                             __bf16* __restrict__ Bpi1, __bf16* __restrict__ Bpi2,
                             __bf16* __restrict__ Bpo1, __bf16* __restrict__ Bpo2,
                             float* __restrict__ dwT12, float* __restrict__ dwb12,
                             __bf16* __restrict__ Bpk) {
    int idx = blockIdx.x * 256 + threadIdx.x;
    if (idx < 147456) {   // conv1: Bc1[oc][t*128+ic]
        int oc = idx / 1152, k = idx % 1152;
        int t = k >> 7, ic = k & 127;
        Bc1[idx] = (__bf16)c1w[(oc * 128 + ic) * 9 + t];
        return;
    }
    idx -= 147456;
    if (idx < 16384) { Bpi1[idx] = (__bf16)pi1[idx]; return; }
    idx -= 16384;
    if (idx < 16384) { Bpi2[idx] = (__bf16)pi2[idx]; return; }
    idx -= 16384;
    if (idx < 16384) { Bpo1[idx] = (__bf16)po1[idx]; return; }
    idx -= 16384;
    if (idx < 16384) { Bpo2[idx] = (__bf16)po2[idx]; return; }
    idx -= 16384;
    if (idx < 4608) {   // dwT12[t][c512]
        int t = idx / 512, c = idx % 512;
        dwT12[t * C8 + c] = (c < 256) ? dw1[c * 9 + t] : dw2[(c - 256) * 9 + t];
        return;
    }
    idx -= 4608;
    if (idx < 512) { dwb12[idx] = (idx < 256) ? dw1b[idx] : dw2b[idx - 256]; return; }
    idx -= 512;
    if (idx < 32768) {   // Bpk: po weights pre-packed in MFMA B-fragment order
        int j = idx & 7, ln = (idx >> 3) & 63, nt = (idx >> 9) & 3, kg = (idx >> 11) & 3, cc = idx >> 13;
        int lmx = ln & 15, lqx = ln >> 4;
        int oc = nt * 16 + lmx;
        int ci = (cc & 1) * 128 + kg * 32 + lqx * 8 + j;
        const float* src = (cc >> 1) ? po2 : po1;
        Bpk[idx] = (__bf16)src[oc * C4 + ci];
    }
}

// ---------------- feature planar fp32 -> pixel-major bf16 [bf][p][64] ----------------
__global__ void featPM_kernel(const float* __restrict__ feat, __bf16* __restrict__ featPM) {
    __shared__ float Lt[64 * 68];
    int bf = blockIdx.x / 400;            // b*TT+f, 0..15
    int p0 = (blockIdx.x % 400) * 64;
    int tid = threadIdx.x;
    int c = tid & 63, half = tid >> 6;
    const float* src = feat + ((size_t)bf * CC + c) * HWW + p0 + half * 16;
    #pragma unroll
    for (int k = 0; k < 16; k++) Lt[(half * 16 + k) * 68 + c] = src[k];
    __syncthreads();
    int cg = tid & 7;
    #pragma unroll
    for (int pass = 0; pass < 2; pass++) {
        int pl = (tid >> 3) + pass * 32;
        bf16x8 o;
        #pragma unroll
        for (int j = 0; j < 8; j++) o[j] = (__bf16)Lt[pl * 68 + cg * 8 + j];
        *(bf16x8*)(featPM + ((size_t)bf * HWW + p0 + pl) * CC + cg * 8) = o;
    }
}

// ---------------- dynamic depthwise conv: src (bf16 PM) -> fpPM (bf16 PM) ----------------
__global__ void dyndw_kernel(const __bf16* __restrict__ src, size_t bstr,
                             const float* __restrict__ wdT, const float* __restrict__ kc_bias,
                             __bf16* __restrict__ fpPM, int fx) {
    int gi = blockIdx.x * 256 + threadIdx.x;   // BB*HWW*8
    int c0 = (gi & 7) * 8;
    int rem = gi >> 3;
    int p = rem % HWW;
    int bb = rem / HWW;
    int py = p / WW, px = p % WW;
    float acc[8];
    float4 k0 = *(const float4*)(kc_bias + c0);
    float4 k1 = *(const float4*)(kc_bias + c0 + 4);
    acc[0]=k0.x; acc[1]=k0.y; acc[2]=k0.z; acc[3]=k0.w;
    acc[4]=k1.x; acc[5]=k1.y; acc[6]=k1.z; acc[7]=k1.w;
    const float* wb = wdT + (size_t)(bb * NSTEP + fx) * 576;
    const __bf16* sb = src + (size_t)bb * bstr;
    const int dyA[9] = {-1,-1,-1,0,0,0,1,1,1};
    const int dxA[9] = {-1,0,1,-1,0,1,-1,0,1};
    #pragma unroll
    for (int t = 0; t < 9; t++) {
        int dy = dyA[t], dx = dxA[t];
        if ((unsigned)(py + dy) < HH && (unsigned)(px + dx) < WW) {
            bf16x8 uv = *(const bf16x8*)(sb + (size_t)(p + dy * WW + dx) * CC + c0);
            float4 w0 = *(const float4*)(wb + t * CC + c0);
            float4 w1 = *(const float4*)(wb + t * CC + c0 + 4);
            acc[0] += (float)uv[0] * w0.x; acc[1] += (float)uv[1] * w0.y;
            acc[2] += (float)uv[2] * w0.z; acc[3] += (float)uv[3] * w0.w;
            acc[4] += (float)uv[4] * w1.x; acc[5] += (float)uv[5] * w1.y;
            acc[6] += (float)uv[6] * w1.z; acc[7] += (float)uv[7] * w1.w;
        }
    }
    bf16x8 o;
    #pragma unroll
    for (int j = 0; j < 8; j++) o[j] = (__bf16)acc[j];
    *(bf16x8*)(fpPM + ((size_t)bb * HWW + p) * CC + c0) = o;
}

// ---------------- conv1 implicit-GEMM: M=64px tile, N=128, K=1152, 256 thr, grid BB*400 ----------------
// Round-5 2-barrier staged structure, halved M-tile -> 800 blocks = 3.1/CU (2x latency hiding).
__global__ void conv1_gemm(const __bf16* __restrict__ featPM, const __bf16* __restrict__ fpPM,
                           const __bf16* __restrict__ Bc1, const float* __restrict__ bias,
                           __bf16* __restrict__ fusionPM, int fx) {
    __shared__ __align__(16) __bf16 As[64 * 40];
    __shared__ __align__(16) __bf16 Bs[128 * 40];
    const int tid = threadIdx.x;
    const int bid = blockIdx.x;
    const int wg = (bid & 7) * 100 + (bid >> 3);   // bijective XCD swizzle (800 % 8 == 0)
    const int bb = wg / 400;
    const int p0 = (wg % 400) * 64;
    const int ia = tid >> 2, ha = tid & 3;         // A: row 0..63, 8-elem quarter
    const int ib = tid >> 1, hb = tid & 1;         // B: row 0..127, 16-elem half
    const int p = p0 + ia;
    const int py = p / WW, px = p % WW;
    const __bf16* featB = featPM + (size_t)(bb * TT + fx) * HWW * CC;
    const __bf16* fpB   = fpPM + (size_t)bb * HWW * CC;
    const int wv = tid >> 6, lane = tid & 63, lm = lane & 15, lq = lane >> 4;
    f32x4 acc[8];
    #pragma unroll
    for (int nt = 0; nt < 8; nt++) acc[nt] = (f32x4){0.f, 0.f, 0.f, 0.f};

    for (int ks = 0; ks < 36; ks++) {
        const int t = ks >> 2, ci0 = (ks & 3) * 32;
        const int dy = t / 3 - 1, dx = t % 3 - 1;
        const bool valid = ((unsigned)(py + dy) < HH) && ((unsigned)(px + dx) < WW);
        uint4 a0 = {0,0,0,0};
        if (valid) {
            const __bf16* sp = (ci0 < 64)
                ? featB + (size_t)(p + dy * WW + dx) * CC + ci0
                : fpB   + (size_t)(p + dy * WW + dx) * CC + (ci0 - 64);
            a0 = *(const uint4*)(sp + ha * 8);
        }
        const __bf16* bp = Bc1 + (size_t)ib * 1152 + ks * 32 + hb * 16;
        uint4 w0q = *(const uint4*)(bp);
        uint4 w1q = *(const uint4*)(bp + 8);
        __syncthreads();
        *(uint4*)&As[ia * 40 + ha * 8] = a0;
        *(uint4*)&Bs[ib * 40 + hb * 16]     = w0q;
        *(uint4*)&Bs[ib * 40 + hb * 16 + 8] = w1q;
        __syncthreads();
        bf16x8 af = *(const bf16x8*)&As[(wv * 16 + lm) * 40 + lq * 8];
        #pragma unroll
        for (int nt = 0; nt < 8; nt++) {
            bf16x8 bfr = *(const bf16x8*)&Bs[(nt * 16 + lm) * 40 + lq * 8];
            acc[nt] = mfma16(af, bfr, acc[nt]);
        }
    }
    __bf16* ob = fusionPM + (size_t)bb * HWW * C2;
    #pragma unroll
    for (int nt = 0; nt < 8; nt++) {
        const int oc = nt * 16 + lm;
        const float bs = bias[oc];
        #pragma unroll
        for (int r = 0; r < 4; r++) {
            const int pp = p0 + wv * 16 + lq * 4 + r;
            float v = acc[nt][r] + bs;
            v = v > 0.f ? v : 0.1f * v;
            ob[(size_t)pp * C2 + oc] = (__bf16)v;
        }
    }
}

// ---------------- pw1 fused both branches: u12 = fusion_half @ pi^T + b (bf16 out) ----------------
// grid: BB * 200 * 4  (nb: branch = nb>>1, sub-half = nb&1)
__global__ void pw1_gemm(const __bf16* __restrict__ fusionPM,
                         const __bf16* __restrict__ Bpi1, const __bf16* __restrict__ Bpi2,
                         const float* __restrict__ pi1b, const float* __restrict__ pi2b,
                         __bf16* __restrict__ u12PM) {
    __shared__ __align__(16) __bf16 As[128 * 40];
    __shared__ __align__(16) __bf16 Bs[128 * 40];
    const int tid = threadIdx.x;
    const int bb = blockIdx.x / 800;
    const int rem = blockIdx.x % 800;
    const int p0 = (rem >> 2) * 128;
    const int nb = rem & 3;
    const int br = nb >> 1, ns = nb & 1;
    const __bf16* Bpi = br ? Bpi2 : Bpi1;
    const float* bias = br ? pi2b : pi1b;
    const int i = tid >> 1, h = tid & 1;
    const int p = p0 + i;
    const __bf16* fB = fusionPM + (size_t)bb * HWW * C2 + br * CC;
    const int wv = tid >> 6, lane = tid & 63, lm = lane & 15, lq = lane >> 4;
    f32x4 acc[2][8];
    #pragma unroll
    for (int mt = 0; mt < 2; mt++)
        #pragma unroll
        for (int nt = 0; nt < 8; nt++) acc[mt][nt] = (f32x4){0.f, 0.f, 0.f, 0.f};

    #pragma unroll
    for (int ks = 0; ks < 2; ks++) {
        const int ci0 = ks * 32;
        const __bf16* sp = fB + (size_t)p * C2 + ci0 + h * 16;
        uint4 a0 = *(const uint4*)(sp);
        uint4 a1 = *(const uint4*)(sp + 8);
        const __bf16* bp = Bpi + (size_t)(ns * 128 + i) * 64 + ci0 + h * 16;
        uint4 w0q = *(const uint4*)(bp);
        uint4 w1q = *(const uint4*)(bp + 8);
        __syncthreads();
        *(uint4*)&As[i * 40 + h * 16]     = a0;
        *(uint4*)&As[i * 40 + h * 16 + 8] = a1;
        *(uint4*)&Bs[i * 40 + h * 16]     = w0q;
        *(uint4*)&Bs[i * 40 + h * 16 + 8] = w1q;
        __syncthreads();
        bf16x8 af0 = *(const bf16x8*)&As[((wv * 2 + 0) * 16 + lm) * 40 + lq * 8];
        bf16x8 af1 = *(const bf16x8*)&As[((wv * 2 + 1) * 16 + lm) * 40 + lq * 8];
        #pragma unroll
        for (int nt = 0; nt < 8; nt++) {
            bf16x8 bf = *(const bf16x8*)&Bs[(nt * 16 + lm) * 40 + lq * 8];
            acc[0][nt] = mfma16(af0, bf, acc[0][nt]);
            acc[1][nt] = mfma16(af1, bf, acc[1][nt]);
        }
    }
    __bf16* ub = u12PM + (size_t)bb * HWW * C8;
    #pragma unroll
    for (int mt = 0; mt < 2; mt++) {
        #pragma unroll
        for (int nt = 0; nt < 8; nt++) {
            const int ocl = ns * 128 + nt * 16 + lm;      // within branch's 256
            const int oc = br * 256 + ocl;                // within 512
            const float bs = bias[ocl];
            #pragma unroll
            for (int r = 0; r < 4; r++) {
                const int pp = p0 + (wv * 2 + mt) * 16 + lq * 4 + r;
                ub[(size_t)pp * C8 + oc] = (__bf16)(acc[mt][nt][r] + bs);
            }
        }
    }
}

// ---------------- fused dw3x3 + pw2 + gate epilogue, 32-px tiles, LDS-staged u ----------------
// grid BB*800 (XCD-swizzled). Per chunk of 128 ch: stage u[3][34][128] -> LDS (OOB zero-filled),
// guard-free 9-tap dw via ds_read_b128 + v_pk_fma_f32, Vt -> MFMA vs frag-packed Bpk.
__global__ void dwpw2_gemm(const __bf16* __restrict__ u12PM,
                           const float* __restrict__ dwT12, const float* __restrict__ dwb12,
                           const __bf16* __restrict__ Bpk,
                           const float* __restrict__ pob1, const float* __restrict__ pob2,
                           const __bf16* __restrict__ fusionPM,
                           float* __restrict__ out, __bf16* __restrict__ outPM, int fx) {
    __shared__ __align__(16) __bf16 uL[3 * 34 * 128];   // 26112 B
    __shared__ __align__(16) __bf16 Vt[32 * 136];       //  8704 B
    const int tid = threadIdx.x;
    const int bid = blockIdx.x;
    const int wg = (bid & 7) * 200 + (bid >> 3);        // bijective XCD swizzle (1600 % 8 == 0)
    const int bb = wg / 800;
    const int p0 = (wg % 800) * 32;                     // strip: 32 px within one image row
    const int py = p0 / WW, px0 = p0 % WW;
    const __bf16* uB = u12PM + (size_t)bb * HWW * C8;
    const int wv = tid >> 6, lane = tid & 63, lm = lane & 15, lq = lane >> 4;
    const int mt = wv & 1, nh = wv >> 1;
    const int cg = tid & 15, prow = tid >> 4;           // ch-group 0..15, px 0..15 (+16)

    f32x4 acc[2][2];   // [branch][ntl]
    #pragma unroll
    for (int b = 0; b < 2; b++)
        #pragma unroll
        for (int n = 0; n < 2; n++) acc[b][n] = (f32x4){0.f, 0.f, 0.f, 0.f};

    const int rbase = py - 1, cbase = px0 - 1;

    #pragma unroll
    for (int cc = 0; cc < 4; cc++) {
        // ---- stage u chunk: rows py-1..py+1, cols px0-1..px0+32, ch [cc*128,+128) ----
        const int c0ch = cc * 128;
        #pragma unroll
        for (int it = 0; it < 7; it++) {
            int idx = it * 256 + tid;                   // 1632 16B-chunks
            if (idx < 1632) {
                int s = idx >> 4, part = idx & 15;
                int r = s / 34, c = s - r * 34;
                int gr = rbase + r, gc = cbase + c;
                uint4 v = {0,0,0,0};
                if ((unsigned)gr < HH && (unsigned)gc < WW)
                    v = *(const uint4*)(uB + (size_t)(gr * WW + gc) * C8 + c0ch + part * 8);
                *(uint4*)&uL[idx * 8] = v;
            }
        }
        __syncthreads();   // uL ready; also guarantees prev chunk's MFMA Vt-reads done

        // ---- dw 3x3: guard-free, packed fma ----
        const int c0 = c0ch + cg * 8;
        f32x2 a0[4], a1[4];
        {
            float4 b0 = *(const float4*)(dwb12 + c0);
            float4 b1 = *(const float4*)(dwb12 + c0 + 4);
            a0[0] = (f32x2){b0.x, b0.y}; a0[1] = (f32x2){b0.z, b0.w};
            a0[2] = (f32x2){b1.x, b1.y}; a0[3] = (f32x2){b1.z, b1.w};
            #pragma unroll
            for (int k = 0; k < 4; k++) a1[k] = a0[k];
        }
        #pragma unroll
        for (int t = 0; t < 9; t++) {
            const int dy = t / 3 - 1, dx = t % 3 - 1;
            float4 w0 = *(const float4*)(dwT12 + t * C8 + c0);
            float4 w1 = *(const float4*)(dwT12 + t * C8 + c0 + 4);
            f32x2 wp[4] = {(f32x2){w0.x, w0.y}, (f32x2){w0.z, w0.w},
                           (f32x2){w1.x, w1.y}, (f32x2){w1.z, w1.w}};
            const int base = ((1 + dy) * 34 + 1 + dx) * 128 + cg * 8;
            uint4 ua = *(const uint4*)&uL[base + prow * 128];
            uint4 ub4 = *(const uint4*)&uL[base + (prow + 16) * 128];
            bpk_fma(ua.x, wp[0], a0[0]); bpk_fma(ua.y, wp[1], a0[1]);
            bpk_fma(ua.z, wp[2], a0[2]); bpk_fma(ua.w, wp[3], a0[3]);
            bpk_fma(ub4.x, wp[0], a1[0]); bpk_fma(ub4.y, wp[1], a1[1]);
            bpk_fma(ub4.z, wp[2], a1[2]); bpk_fma(ub4.w, wp[3], a1[3]);
        }
        bf16x8 o0, o1;
        #pragma unroll
        for (int k = 0; k < 4; k++) {
            o0[2 * k] = (__bf16)a0[k].x; o0[2 * k + 1] = (__bf16)a0[k].y;
            o1[2 * k] = (__bf16)a1[k].x; o1[2 * k + 1] = (__bf16)a1[k].y;
        }
        *(bf16x8*)&Vt[prow * 136 + cg * 8]        = o0;
        *(bf16x8*)&Vt[(16 + prow) * 136 + cg * 8] = o1;
        __syncthreads();

        // ---- MFMA for this chunk's branch ----
        const int br = cc >> 1;
        const __bf16* bbase = Bpk + cc * 8192 + (size_t)lane * 8;
        #pragma unroll
        for (int kg = 0; kg < 4; kg++) {
            bf16x8 af = *(const bf16x8*)&Vt[(mt * 16 + lm) * 136 + kg * 32 + lq * 8];
            #pragma unroll
            for (int ntl = 0; ntl < 2; ntl++) {
                bf16x8 bfr = *(const bf16x8*)(bbase + kg * 2048 + (nh * 2 + ntl) * 512);
                acc[br][ntl] = mfma16(af, bfr, acc[br][ntl]);
            }
        }
    }
    // ---- epilogue: gate + combine ----
    const __bf16* fB = fusionPM + (size_t)bb * HWW * C2;
    __bf16* opB = outPM + (size_t)bb * HWW * CC;
    float* outp = out + (size_t)(bb * TT + fx) * CC * HWW;
    const int ppb = p0 + mt * 16 + lq * 4;
    #pragma unroll
    for (int ntl = 0; ntl < 2; ntl++) {
        const int oc = (nh * 2 + ntl) * 16 + lm;
        const float bs1 = pob1[oc];
        const float bs2 = pob2[oc];
        float4 vo;
        #pragma unroll
        for (int r = 0; r < 4; r++) {
            const int pp = ppb + r;
            float g1 = 1.f / (1.f + __expf(-(acc[0][ntl][r] + bs1)));
            float g2 = 1.f / (1.f + __expf(-(acc[1][ntl][r] + bs2)));
            float f1 = (float)fB[(size_t)pp * C2 + oc];
            float f2 = (float)fB[(size_t)pp * C2 + CC + oc];
            float val = f1 * g1 + f2 * g2;
            (&vo.x)[r] = val;
            opB[(size_t)pp * CC + oc] = (__bf16)val;
        }
        *(float4*)(outp + (size_t)oc * HWW + ppb) = vo;
    }
}

extern "C" void kernel_launch(void* const* d_in, const int* in_sizes, int n_in,
                              void* d_out, int out_size, void* d_ws, size_t ws_size,
                              hipStream_t stream) {
    const float* feat     = (const float*)d_in[0];
    const float* kc_w1    = (const float*)d_in[1];
    const float* kc_g     = (const float*)d_in[2];
    const float* kc_be    = (const float*)d_in[3];
    const float* kc_mu    = (const float*)d_in[4];
    const float* kc_var   = (const float*)d_in[5];
    const float* kc_w2    = (const float*)d_in[6];
    const float* kc_b2    = (const float*)d_in[7];
    const float* kc_bias  = (const float*)d_in[8];
    const float* conv1_w  = (const float*)d_in[9];
    const float* conv1_b  = (const float*)d_in[10];
    const float* pi1_w    = (const float*)d_in[11];
    const float* pi1_b    = (const float*)d_in[12];
    const float* dw1_w    = (const float*)d_in[13];
    const float* dw1_b    = (const float*)d_in[14];
    const float* po1_w    = (const float*)d_in[15];
    const float* po1_b    = (const float*)d_in[16];
    const float* pi2_w    = (const float*)d_in[17];
    const float* pi2_b    = (const float*)d_in[18];
    const float* dw2_w    = (const float*)d_in[19];
    const float* dw2_b    = (const float*)d_in[20];
    const float* po2_w    = (const float*)d_in[21];
    const float* po2_b    = (const float*)d_in[22];
    float* out = (float*)d_out;

    char* W = (char*)d_ws;
    __bf16* featPM   = (__bf16*)W; W += (size_t)BB * TT * HWW * CC * 2;   // 52.4 MB
    __bf16* fpPM     = (__bf16*)W; W += (size_t)BB * HWW * CC * 2;        //  6.6 MB
    __bf16* fusionPM = (__bf16*)W; W += (size_t)BB * HWW * C2 * 2;        // 13.1 MB
    __bf16* u12PM    = (__bf16*)W; W += (size_t)BB * HWW * C8 * 2;        // 52.4 MB (bf16)
    __bf16* outPM    = (__bf16*)W; W += (size_t)BB * HWW * CC * 2;        //  6.6 MB
    __bf16* Bc1      = (__bf16*)W; W += 294912;
    __bf16* Bpi1     = (__bf16*)W; W += 32768;
    __bf16* Bpi2     = (__bf16*)W; W += 32768;
    __bf16* Bpo1     = (__bf16*)W; W += 32768;
    __bf16* Bpo2     = (__bf16*)W; W += 32768;
    __bf16* Bpk      = (__bf16*)W; W += 65536;
    float*  dwT12    = (float*)W;  W += 18432;
    float*  dwb12    = (float*)W;  W += 2048;
    float*  poolb    = (float*)W;  W += 4096;
    float*  wdT      = (float*)W;  W += 32256;

    prep_weights<<<980, 256, 0, stream>>>(conv1_w, pi1_w, pi2_w, po1_w, po2_w, dw1_w, dw2_w,
                                          dw1_b, dw2_b,
                                          Bc1, Bpi1, Bpi2, Bpo1, Bpo2, dwT12, dwb12, Bpk);
    featPM_kernel<<<BB * TT * 400, 256, 0, stream>>>(feat, featPM);
    pool_kernel<<<BB * NSTEP * CC, 256, 0, stream>>>(feat, poolb);
    wd_kernel<<<BB * NSTEP, 64, 0, stream>>>(poolb, kc_w1, kc_g, kc_be, kc_mu, kc_var, kc_w2, kc_b2, wdT);
    copy_init_kernel<<<BB * CHW / 4 / 256, 256, 0, stream>>>(feat, out);

    for (int i = 0; i < NSTEP; i++) {
        int fx = NSTEP - 1 - i;   // 6..0
        const __bf16* src = (fx == NSTEP - 1) ? (featPM + (size_t)(TT - 1) * HWW * CC) : outPM;
        size_t bstr = (fx == NSTEP - 1) ? (size_t)TT * HWW * CC : (size_t)HWW * CC;
        dyndw_kernel<<<BB * HWW * 8 / 256, 256, 0, stream>>>(src, bstr, wdT, kc_bias, fpPM, fx);
        conv1_gemm<<<BB * 400, 256, 0, stream>>>(featPM, fpPM, Bc1, conv1_b, fusionPM, fx);
        pw1_gemm<<<BB * 800, 256, 0, stream>>>(fusionPM, Bpi1, Bpi2, pi1_b, pi2_b, u12PM);
        dwpw2_gemm<<<BB * 800, 256, 0, stream>>>(u12PM, dwT12, dwb12, Bpk, po1_b, po2_b, fusionPM, out, outPM, fx);
    }
}

// Round 10
// 983.359 us; speedup vs baseline: 1.3365x; 1.0604x over previous
//
#include <hip/hip_runtime.h>

typedef __attribute__((ext_vector_type(8))) __bf16 bf16x8;
typedef __attribute__((ext_vector_type(4))) float f32x4;
typedef __attribute__((ext_vector_type(2))) float f32x2;

#define BB 2
#define TT 8
#define CC 64
#define HH 160
#define WW 160
#define HWW 25600
#define RR 16
#define C2 128
#define C4 256
#define C8 512
#define NSTEP 7
#define CHW (CC*HWW)
#define EPSV 1e-5f

__device__ __forceinline__ f32x4 mfma16(bf16x8 a, bf16x8 b, f32x4 c) {
    return __builtin_amdgcn_mfma_f32_16x16x32_bf16(a, b, c, 0, 0, 0);
}

// unpack 2 bf16 (one dword) -> f32x2 and fma with packed weights (v_pk_fma_f32)
__device__ __forceinline__ void bpk_fma(unsigned d, f32x2 w, f32x2& a) {
    f32x2 u;
    u.x = __uint_as_float(d << 16);
    u.y = __uint_as_float(d & 0xffff0000u);
    a = __builtin_elementwise_fma(u, w, a);
}

// ---------------- pool: mean over H,W for frames 0..6 (fp32 planar input) ----------------
__global__ void pool_kernel(const float* __restrict__ feat, float* __restrict__ pool) {
    int idx = blockIdx.x;                 // b*NSTEP*CC + f*CC + c
    int b = idx / (NSTEP * CC);
    int f = (idx / CC) % NSTEP;
    int c = idx % CC;
    const float4* src = (const float4*)(feat + ((size_t)(b * TT + f) * CC + c) * HWW);
    float s = 0.f;
    for (int i = threadIdx.x; i < HWW / 4; i += 256) {
        float4 v = src[i];
        s += v.x + v.y + v.z + v.w;
    }
    __shared__ float sm[256];
    sm[threadIdx.x] = s;
    __syncthreads();
    for (int off = 128; off > 0; off >>= 1) {
        if (threadIdx.x < off) sm[threadIdx.x] += sm[threadIdx.x + off];
        __syncthreads();
    }
    if (threadIdx.x == 0) pool[idx] = sm[0] * (1.0f / HWW);
}

// ---------------- dynamic depthwise weights -> wdT[bf][t][c] (fp32) ----------------
__global__ void wd_kernel(const float* __restrict__ pool, const float* __restrict__ w1,
                          const float* __restrict__ gamma, const float* __restrict__ beta,
                          const float* __restrict__ mean, const float* __restrict__ var,
                          const float* __restrict__ w2, const float* __restrict__ b2,
                          float* __restrict__ wdT) {
    int bf = blockIdx.x;                  // 0..BB*NSTEP-1
    __shared__ float z[RR];
    int tid = threadIdx.x;                // 64 threads
    if (tid < RR) {
        const float* p = pool + bf * CC;
        float s = 0.f;
        for (int c = 0; c < CC; c++) s += p[c] * w1[tid * CC + c];
        s = (s - mean[tid]) * rsqrtf(var[tid] + EPSV) * gamma[tid] + beta[tid];
        z[tid] = s > 0.f ? s : 0.f;
    }
    __syncthreads();
    for (int o = tid; o < CC * 9; o += 64) {
        float s = b2[o];
        #pragma unroll
        for (int r = 0; r < RR; r++) s += z[r] * w2[o * RR + r];
        int c = o / 9, t = o % 9;
        wdT[bf * 576 + t * CC + c] = s;
    }
}

// ---------------- copy init slice (t=7) fp32 planar into output ----------------
__global__ void copy_init_kernel(const float* __restrict__ feat, float* __restrict__ out) {
    int i = blockIdx.x * 256 + threadIdx.x;   // over BB*CHW/4
    int n4 = CHW / 4;
    int b = i / n4;
    int r = i % n4;
    size_t off = ((size_t)(b * TT + (TT - 1)) * CHW) / 4 + r;
    ((float4*)out)[off] = ((const float4*)feat)[off];
}

// ---------------- prep weights: Bc1 [oc][t*128+ic] (round-5 layout) + dw/po packs ----------------
__global__ void prep_weights(const float* __restrict__ c1w,
                             const float* __restrict__ pi1, const float* __restrict__ pi2,
                             const float* __restrict__ po1, const float* __restrict__ po2,
                             const float* __restrict__ dw1, const float* __restrict__ dw2,
                             const float* __restrict__ dw1b, const float* __restrict__ dw2b,
                             __bf16* __restrict__ Bc1,
                             __bf16* __restrict__ Bpi1, __bf16* __restrict__ Bpi2,
                             __bf16* __restrict__ Bpo1, __bf16* __restrict__ Bpo2,
                             float* __restrict__ dwT12, float* __restrict__ dwb12,
                             __bf16* __restrict__ Bpk) {
    int idx = blockIdx.x * 256 + threadIdx.x;
    if (idx < 147456) {   // conv1: Bc1[oc][t*128+ic]
        int oc = idx / 1152, k = idx % 1152;
        int t = k >> 7, ic = k & 127;
        Bc1[idx] = (__bf16)c1w[(oc * 128 + ic) * 9 + t];
        return;
    }
    idx -= 147456;
    if (idx < 16384) { Bpi1[idx] = (__bf16)pi1[idx]; return; }
    idx -= 16384;
    if (idx < 16384) { Bpi2[idx] = (__bf16)pi2[idx]; return; }
    idx -= 16384;
    if (idx < 16384) { Bpo1[idx] = (__bf16)po1[idx]; return; }
    idx -= 16384;
    if (idx < 16384) { Bpo2[idx] = (__bf16)po2[idx]; return; }
    idx -= 16384;
    if (idx < 4608) {   // dwT12[t][c512]
        int t = idx / 512, c = idx % 512;
        dwT12[t * C8 + c] = (c < 256) ? dw1[c * 9 + t] : dw2[(c - 256) * 9 + t];
        return;
    }
    idx -= 4608;
    if (idx < 512) { dwb12[idx] = (idx < 256) ? dw1b[idx] : dw2b[idx - 256]; return; }
    idx -= 512;
    if (idx < 32768) {   // Bpk: po weights pre-packed in MFMA B-fragment order
        int j = idx & 7, ln = (idx >> 3) & 63, nt = (idx >> 9) & 3, kg = (idx >> 11) & 3, cc = idx >> 13;
        int lmx = ln & 15, lqx = ln >> 4;
        int oc = nt * 16 + lmx;
        int ci = (cc & 1) * 128 + kg * 32 + lqx * 8 + j;
        const float* src = (cc >> 1) ? po2 : po1;
        Bpk[idx] = (__bf16)src[oc * C4 + ci];
    }
}

// ---------------- feature planar fp32 -> pixel-major bf16 [bf][p][64] ----------------
__global__ void featPM_kernel(const float* __restrict__ feat, __bf16* __restrict__ featPM) {
    __shared__ float Lt[64 * 68];
    int bf = blockIdx.x / 400;            // b*TT+f, 0..15
    int p0 = (blockIdx.x % 400) * 64;
    int tid = threadIdx.x;
    int c = tid & 63, half = tid >> 6;
    const float* src = feat + ((size_t)bf * CC + c) * HWW + p0 + half * 16;
    #pragma unroll
    for (int k = 0; k < 16; k++) Lt[(half * 16 + k) * 68 + c] = src[k];
    __syncthreads();
    int cg = tid & 7;
    #pragma unroll
    for (int pass = 0; pass < 2; pass++) {
        int pl = (tid >> 3) + pass * 32;
        bf16x8 o;
        #pragma unroll
        for (int j = 0; j < 8; j++) o[j] = (__bf16)Lt[pl * 68 + cg * 8 + j];
        *(bf16x8*)(featPM + ((size_t)bf * HWW + p0 + pl) * CC + cg * 8) = o;
    }
}

// ---------------- dynamic depthwise conv: src (bf16 PM) -> fpPM (bf16 PM) ----------------
__global__ void dyndw_kernel(const __bf16* __restrict__ src, size_t bstr,
                             const float* __restrict__ wdT, const float* __restrict__ kc_bias,
                             __bf16* __restrict__ fpPM, int fx) {
    int gi = blockIdx.x * 256 + threadIdx.x;   // BB*HWW*8
    int c0 = (gi & 7) * 8;
    int rem = gi >> 3;
    int p = rem % HWW;
    int bb = rem / HWW;
    int py = p / WW, px = p % WW;
    float acc[8];
    float4 k0 = *(const float4*)(kc_bias + c0);
    float4 k1 = *(const float4*)(kc_bias + c0 + 4);
    acc[0]=k0.x; acc[1]=k0.y; acc[2]=k0.z; acc[3]=k0.w;
    acc[4]=k1.x; acc[5]=k1.y; acc[6]=k1.z; acc[7]=k1.w;
    const float* wb = wdT + (size_t)(bb * NSTEP + fx) * 576;
    const __bf16* sb = src + (size_t)bb * bstr;
    const int dyA[9] = {-1,-1,-1,0,0,0,1,1,1};
    const int dxA[9] = {-1,0,1,-1,0,1,-1,0,1};
    #pragma unroll
    for (int t = 0; t < 9; t++) {
        int dy = dyA[t], dx = dxA[t];
        if ((unsigned)(py + dy) < HH && (unsigned)(px + dx) < WW) {
            bf16x8 uv = *(const bf16x8*)(sb + (size_t)(p + dy * WW + dx) * CC + c0);
            float4 w0 = *(const float4*)(wb + t * CC + c0);
            float4 w1 = *(const float4*)(wb + t * CC + c0 + 4);
            acc[0] += (float)uv[0] * w0.x; acc[1] += (float)uv[1] * w0.y;
            acc[2] += (float)uv[2] * w0.z; acc[3] += (float)uv[3] * w0.w;
            acc[4] += (float)uv[4] * w1.x; acc[5] += (float)uv[5] * w1.y;
            acc[6] += (float)uv[6] * w1.z; acc[7] += (float)uv[7] * w1.w;
        }
    }
    bf16x8 o;
    #pragma unroll
    for (int j = 0; j < 8; j++) o[j] = (__bf16)acc[j];
    *(bf16x8*)(fpPM + ((size_t)bb * HWW + p) * CC + c0) = o;
}

// ---------------- conv1 implicit-GEMM: M=128px, N=128, K=1152, double-buffered 1-barrier pipeline ----------------
// grid BB*200 (XCD-swizzled). Per ks: load ks+1 (global) || MFMA buf[cur] || store buf[cur^1] -> 1 barrier.
__global__ void conv1_gemm(const __bf16* __restrict__ featPM, const __bf16* __restrict__ fpPM,
                           const __bf16* __restrict__ Bc1, const float* __restrict__ bias,
                           __bf16* __restrict__ fusionPM, int fx) {
    __shared__ __align__(16) __bf16 As[2][128 * 40];
    __shared__ __align__(16) __bf16 Bs[2][128 * 40];
    const int tid = threadIdx.x;
    const int bid = blockIdx.x;
    const int wg = (bid & 7) * 50 + (bid >> 3);   // bijective XCD swizzle (400 % 8 == 0)
    const int bb = wg / 200;
    const int p0 = (wg % 200) * 128;
    const int i = tid >> 1, h = tid & 1;
    const int p = p0 + i;
    const int py = p / WW, px = p % WW;
    const __bf16* featB = featPM + (size_t)(bb * TT + fx) * HWW * CC;
    const __bf16* fpB   = fpPM + (size_t)bb * HWW * CC;
    const int wv = tid >> 6, lane = tid & 63, lm = lane & 15, lq = lane >> 4;
    f32x4 acc[2][8];
    #pragma unroll
    for (int mt = 0; mt < 2; mt++)
        #pragma unroll
        for (int nt = 0; nt < 8; nt++) acc[mt][nt] = (f32x4){0.f, 0.f, 0.f, 0.f};

    uint4 a0, a1, w0q, w1q;
    // prologue: load + store ks=0 into buf 0
    {
        const bool valid = (py >= 1) && (px >= 1);   // ks=0: t=0 -> dy=-1, dx=-1
        a0 = (uint4){0,0,0,0}; a1 = (uint4){0,0,0,0};
        if (valid) {
            const __bf16* sp = featB + (size_t)(p - WW - 1) * CC;   // ci0=0
            a0 = *(const uint4*)(sp + h * 16);
            a1 = *(const uint4*)(sp + h * 16 + 8);
        }
        const __bf16* bp = Bc1 + (size_t)i * 1152 + h * 16;
        w0q = *(const uint4*)(bp);
        w1q = *(const uint4*)(bp + 8);
        *(uint4*)&As[0][i * 40 + h * 16]     = a0;
        *(uint4*)&As[0][i * 40 + h * 16 + 8] = a1;
        *(uint4*)&Bs[0][i * 40 + h * 16]     = w0q;
        *(uint4*)&Bs[0][i * 40 + h * 16 + 8] = w1q;
    }
    __syncthreads();

    for (int ks = 0; ks < 36; ks++) {
        const int cur = ks & 1;
        // issue next-ks global loads (hidden under MFMA)
        if (ks < 35) {
            const int kn = ks + 1;
            const int t = kn >> 2, ci0 = (kn & 3) * 32;
            const int dy = t / 3 - 1, dx = t % 3 - 1;
            const bool valid = ((unsigned)(py + dy) < HH) && ((unsigned)(px + dx) < WW);
            a0 = (uint4){0,0,0,0}; a1 = (uint4){0,0,0,0};
            if (valid) {
                const __bf16* sp = (ci0 < 64)
                    ? featB + (size_t)(p + dy * WW + dx) * CC + ci0
                    : fpB   + (size_t)(p + dy * WW + dx) * CC + (ci0 - 64);
                a0 = *(const uint4*)(sp + h * 16);
                a1 = *(const uint4*)(sp + h * 16 + 8);
            }
            const __bf16* bp = Bc1 + (size_t)i * 1152 + kn * 32 + h * 16;
            w0q = *(const uint4*)(bp);
            w1q = *(const uint4*)(bp + 8);
        }
        // MFMA on current buffer
        bf16x8 af0 = *(const bf16x8*)&As[cur][((wv * 2 + 0) * 16 + lm) * 40 + lq * 8];
        bf16x8 af1 = *(const bf16x8*)&As[cur][((wv * 2 + 1) * 16 + lm) * 40 + lq * 8];
        #pragma unroll
        for (int nt = 0; nt < 8; nt++) {
            bf16x8 bfr = *(const bf16x8*)&Bs[cur][(nt * 16 + lm) * 40 + lq * 8];
            acc[0][nt] = mfma16(af0, bfr, acc[0][nt]);
            acc[1][nt] = mfma16(af1, bfr, acc[1][nt]);
        }
        // store next-ks into other buffer
        if (ks < 35) {
            const int nb = cur ^ 1;
            *(uint4*)&As[nb][i * 40 + h * 16]     = a0;
            *(uint4*)&As[nb][i * 40 + h * 16 + 8] = a1;
            *(uint4*)&Bs[nb][i * 40 + h * 16]     = w0q;
            *(uint4*)&Bs[nb][i * 40 + h * 16 + 8] = w1q;
        }
        __syncthreads();
    }

    __bf16* ob = fusionPM + (size_t)bb * HWW * C2;
    #pragma unroll
    for (int mt = 0; mt < 2; mt++) {
        #pragma unroll
        for (int nt = 0; nt < 8; nt++) {
            const int oc = nt * 16 + lm;
            const float bs = bias[oc];
            #pragma unroll
            for (int r = 0; r < 4; r++) {
                const int pp = p0 + (wv * 2 + mt) * 16 + lq * 4 + r;
                float v = acc[mt][nt][r] + bs;
                v = v > 0.f ? v : 0.1f * v;
                ob[(size_t)pp * C2 + oc] = (__bf16)v;
            }
        }
    }
}

// ---------------- pw1 fused both branches: u12 = fusion_half @ pi^T + b (bf16 out) ----------------
// grid: BB * 200 * 4  (nb: branch = nb>>1, sub-half = nb&1)
__global__ void pw1_gemm(const __bf16* __restrict__ fusionPM,
                         const __bf16* __restrict__ Bpi1, const __bf16* __restrict__ Bpi2,
                         const float* __restrict__ pi1b, const float* __restrict__ pi2b,
                         __bf16* __restrict__ u12PM) {
    __shared__ __align__(16) __bf16 As[128 * 40];
    __shared__ __align__(16) __bf16 Bs[128 * 40];
    const int tid = threadIdx.x;
    const int bb = blockIdx.x / 800;
    const int rem = blockIdx.x % 800;
    const int p0 = (rem >> 2) * 128;
    const int nb = rem & 3;
    const int br = nb >> 1, ns = nb & 1;
    const __bf16* Bpi = br ? Bpi2 : Bpi1;
    const float* bias = br ? pi2b : pi1b;
    const int i = tid >> 1, h = tid & 1;
    const int p = p0 + i;
    const __bf16* fB = fusionPM + (size_t)bb * HWW * C2 + br * CC;
    const int wv = tid >> 6, lane = tid & 63, lm = lane & 15, lq = lane >> 4;
    f32x4 acc[2][8];
    #pragma unroll
    for (int mt = 0; mt < 2; mt++)
        #pragma unroll
        for (int nt = 0; nt < 8; nt++) acc[mt][nt] = (f32x4){0.f, 0.f, 0.f, 0.f};

    #pragma unroll
    for (int ks = 0; ks < 2; ks++) {
        const int ci0 = ks * 32;
        const __bf16* sp = fB + (size_t)p * C2 + ci0 + h * 16;
        uint4 a0 = *(const uint4*)(sp);
        uint4 a1 = *(const uint4*)(sp + 8);
        const __bf16* bp = Bpi + (size_t)(ns * 128 + i) * 64 + ci0 + h * 16;
        uint4 w0q = *(const uint4*)(bp);
        uint4 w1q = *(const uint4*)(bp + 8);
        __syncthreads();
        *(uint4*)&As[i * 40 + h * 16]     = a0;
        *(uint4*)&As[i * 40 + h * 16 + 8] = a1;
        *(uint4*)&Bs[i * 40 + h * 16]     = w0q;
        *(uint4*)&Bs[i * 40 + h * 16 + 8] = w1q;
        __syncthreads();
        bf16x8 af0 = *(const bf16x8*)&As[((wv * 2 + 0) * 16 + lm) * 40 + lq * 8];
        bf16x8 af1 = *(const bf16x8*)&As[((wv * 2 + 1) * 16 + lm) * 40 + lq * 8];
        #pragma unroll
        for (int nt = 0; nt < 8; nt++) {
            bf16x8 bf = *(const bf16x8*)&Bs[(nt * 16 + lm) * 40 + lq * 8];
            acc[0][nt] = mfma16(af0, bf, acc[0][nt]);
            acc[1][nt] = mfma16(af1, bf, acc[1][nt]);
        }
    }
    __bf16* ub = u12PM + (size_t)bb * HWW * C8;
    #pragma unroll
    for (int mt = 0; mt < 2; mt++) {
        #pragma unroll
        for (int nt = 0; nt < 8; nt++) {
            const int ocl = ns * 128 + nt * 16 + lm;      // within branch's 256
            const int oc = br * 256 + ocl;                // within 512
            const float bs = bias[ocl];
            #pragma unroll
            for (int r = 0; r < 4; r++) {
                const int pp = p0 + (wv * 2 + mt) * 16 + lq * 4 + r;
                ub[(size_t)pp * C8 + oc] = (__bf16)(acc[mt][nt][r] + bs);
            }
        }
    }
}

// ---------------- fused dw3x3 + pw2 + gate epilogue, 32-px tiles, LDS-staged u ----------------
// grid BB*800 (XCD-swizzled). Per chunk of 128 ch: stage u[3][34][128] -> LDS (OOB zero-filled),
// guard-free 9-tap dw via ds_read_b128 + v_pk_fma_f32, Vt -> MFMA vs frag-packed Bpk.
__global__ void dwpw2_gemm(const __bf16* __restrict__ u12PM,
                           const float* __restrict__ dwT12, const float* __restrict__ dwb12,
                           const __bf16* __restrict__ Bpk,
                           const float* __restrict__ pob1, const float* __restrict__ pob2,
                           const __bf16* __restrict__ fusionPM,
                           float* __restrict__ out, __bf16* __restrict__ outPM, int fx) {
    __shared__ __align__(16) __bf16 uL[3 * 34 * 128];   // 26112 B
    __shared__ __align__(16) __bf16 Vt[32 * 136];       //  8704 B
    const int tid = threadIdx.x;
    const int bid = blockIdx.x;
    const int wg = (bid & 7) * 200 + (bid >> 3);        // bijective XCD swizzle (1600 % 8 == 0)
    const int bb = wg / 800;
    const int p0 = (wg % 800) * 32;                     // strip: 32 px within one image row
    const int py = p0 / WW, px0 = p0 % WW;
    const __bf16* uB = u12PM + (size_t)bb * HWW * C8;
    const int wv = tid >> 6, lane = tid & 63, lm = lane & 15, lq = lane >> 4;
    const int mt = wv & 1, nh = wv >> 1;
    const int cg = tid & 15, prow = tid >> 4;           // ch-group 0..15, px 0..15 (+16)

    f32x4 acc[2][2];   // [branch][ntl]
    #pragma unroll
    for (int b = 0; b < 2; b++)
        #pragma unroll
        for (int n = 0; n < 2; n++) acc[b][n] = (f32x4){0.f, 0.f, 0.f, 0.f};

    const int rbase = py - 1, cbase = px0 - 1;

    #pragma unroll
    for (int cc = 0; cc < 4; cc++) {
        // ---- stage u chunk: rows py-1..py+1, cols px0-1..px0+32, ch [cc*128,+128) ----
        const int c0ch = cc * 128;
        #pragma unroll
        for (int it = 0; it < 7; it++) {
            int idx = it * 256 + tid;                   // 1632 16B-chunks
            if (idx < 1632) {
                int s = idx >> 4, part = idx & 15;
                int r = s / 34, c = s - r * 34;
                int gr = rbase + r, gc = cbase + c;
                uint4 v = {0,0,0,0};
                if ((unsigned)gr < HH && (unsigned)gc < WW)
                    v = *(const uint4*)(uB + (size_t)(gr * WW + gc) * C8 + c0ch + part * 8);
                *(uint4*)&uL[idx * 8] = v;
            }
        }
        __syncthreads();   // uL ready; also guarantees prev chunk's MFMA Vt-reads done

        // ---- dw 3x3: guard-free, packed fma ----
        const int c0 = c0ch + cg * 8;
        f32x2 a0[4], a1[4];
        {
            float4 b0 = *(const float4*)(dwb12 + c0);
            float4 b1 = *(const float4*)(dwb12 + c0 + 4);
            a0[0] = (f32x2){b0.x, b0.y}; a0[1] = (f32x2){b0.z, b0.w};
            a0[2] = (f32x2){b1.x, b1.y}; a0[3] = (f32x2){b1.z, b1.w};
            #pragma unroll
            for (int k = 0; k < 4; k++) a1[k] = a0[k];
        }
        #pragma unroll
        for (int t = 0; t < 9; t++) {
            const int dy = t / 3 - 1, dx = t % 3 - 1;
            float4 w0 = *(const float4*)(dwT12 + t * C8 + c0);
            float4 w1 = *(const float4*)(dwT12 + t * C8 + c0 + 4);
            f32x2 wp[4] = {(f32x2){w0.x, w0.y}, (f32x2){w0.z, w0.w},
                           (f32x2){w1.x, w1.y}, (f32x2){w1.z, w1.w}};
            const int base = ((1 + dy) * 34 + 1 + dx) * 128 + cg * 8;
            uint4 ua = *(const uint4*)&uL[base + prow * 128];
            uint4 ub4 = *(const uint4*)&uL[base + (prow + 16) * 128];
            bpk_fma(ua.x, wp[0], a0[0]); bpk_fma(ua.y, wp[1], a0[1]);
            bpk_fma(ua.z, wp[2], a0[2]); bpk_fma(ua.w, wp[3], a0[3]);
            bpk_fma(ub4.x, wp[0], a1[0]); bpk_fma(ub4.y, wp[1], a1[1]);
            bpk_fma(ub4.z, wp[2], a1[2]); bpk_fma(ub4.w, wp[3], a1[3]);
        }
        bf16x8 o0, o1;
        #pragma unroll
        for (int k = 0; k < 4; k++) {
            o0[2 * k] = (__bf16)a0[k].x; o0[2 * k + 1] = (__bf16)a0[k].y;
            o1[2 * k] = (__bf16)a1[k].x; o1[2 * k + 1] = (__bf16)a1[k].y;
        }
        *(bf16x8*)&Vt[prow * 136 + cg * 8]        = o0;
        *(bf16x8*)&Vt[(16 + prow) * 136 + cg * 8] = o1;
        __syncthreads();

        // ---- MFMA for this chunk's branch ----
        const int br = cc >> 1;
        const __bf16* bbase = Bpk + cc * 8192 + (size_t)lane * 8;
        #pragma unroll
        for (int kg = 0; kg < 4; kg++) {
            bf16x8 af = *(const bf16x8*)&Vt[(mt * 16 + lm) * 136 + kg * 32 + lq * 8];
            #pragma unroll
            for (int ntl = 0; ntl < 2; ntl++) {
                bf16x8 bfr = *(const bf16x8*)(bbase + kg * 2048 + (nh * 2 + ntl) * 512);
                acc[br][ntl] = mfma16(af, bfr, acc[br][ntl]);
            }
        }
    }
    // ---- epilogue: gate + combine ----
    const __bf16* fB = fusionPM + (size_t)bb * HWW * C2;
    __bf16* opB = outPM + (size_t)bb * HWW * CC;
    float* outp = out + (size_t)(bb * TT + fx) * CC * HWW;
    const int ppb = p0 + mt * 16 + lq * 4;
    #pragma unroll
    for (int ntl = 0; ntl < 2; ntl++) {
        const int oc = (nh * 2 + ntl) * 16 + lm;
        const float bs1 = pob1[oc];
        const float bs2 = pob2[oc];
        float4 vo;
        #pragma unroll
        for (int r = 0; r < 4; r++) {
            const int pp = ppb + r;
            float g1 = 1.f / (1.f + __expf(-(acc[0][ntl][r] + bs1)));
            float g2 = 1.f / (1.f + __expf(-(acc[1][ntl][r] + bs2)));
            float f1 = (float)fB[(size_t)pp * C2 + oc];
            float f2 = (float)fB[(size_t)pp * C2 + CC + oc];
            float val = f1 * g1 + f2 * g2;
            (&vo.x)[r] = val;
            opB[(size_t)pp * CC + oc] = (__bf16)val;
        }
        *(float4*)(outp + (size_t)oc * HWW + ppb) = vo;
    }
}

extern "C" void kernel_launch(void* const* d_in, const int* in_sizes, int n_in,
                              void* d_out, int out_size, void* d_ws, size_t ws_size,
                              hipStream_t stream) {
    const float* feat     = (const float*)d_in[0];
    const float* kc_w1    = (const float*)d_in[1];
    const float* kc_g     = (const float*)d_in[2];
    const float* kc_be    = (const float*)d_in[3];
    const float* kc_mu    = (const float*)d_in[4];
    const float* kc_var   = (const float*)d_in[5];
    const float* kc_w2    = (const float*)d_in[6];
    const float* kc_b2    = (const float*)d_in[7];
    const float* kc_bias  = (const float*)d_in[8];
    const float* conv1_w  = (const float*)d_in[9];
    const float* conv1_b  = (const float*)d_in[10];
    const float* pi1_w    = (const float*)d_in[11];
    const float* pi1_b    = (const float*)d_in[12];
    const float* dw1_w    = (const float*)d_in[13];
    const float* dw1_b    = (const float*)d_in[14];
    const float* po1_w    = (const float*)d_in[15];
    const float* po1_b    = (const float*)d_in[16];
    const float* pi2_w    = (const float*)d_in[17];
    const float* pi2_b    = (const float*)d_in[18];
    const float* dw2_w    = (const float*)d_in[19];
    const float* dw2_b    = (const float*)d_in[20];
    const float* po2_w    = (const float*)d_in[21];
    const float* po2_b    = (const float*)d_in[22];
    float* out = (float*)d_out;

    char* W = (char*)d_ws;
    __bf16* featPM   = (__bf16*)W; W += (size_t)BB * TT * HWW * CC * 2;   // 52.4 MB
    __bf16* fpPM     = (__bf16*)W; W += (size_t)BB * HWW * CC * 2;        //  6.6 MB
    __bf16* fusionPM = (__bf16*)W; W += (size_t)BB * HWW * C2 * 2;        // 13.1 MB
    __bf16* u12PM    = (__bf16*)W; W += (size_t)BB * HWW * C8 * 2;        // 52.4 MB (bf16)
    __bf16* outPM    = (__bf16*)W; W += (size_t)BB * HWW * CC * 2;        //  6.6 MB
    __bf16* Bc1      = (__bf16*)W; W += 294912;
    __bf16* Bpi1     = (__bf16*)W; W += 32768;
    __bf16* Bpi2     = (__bf16*)W; W += 32768;
    __bf16* Bpo1     = (__bf16*)W; W += 32768;
    __bf16* Bpo2     = (__bf16*)W; W += 32768;
    __bf16* Bpk      = (__bf16*)W; W += 65536;
    float*  dwT12    = (float*)W;  W += 18432;
    float*  dwb12    = (float*)W;  W += 2048;
    float*  poolb    = (float*)W;  W += 4096;
    float*  wdT      = (float*)W;  W += 32256;

    prep_weights<<<980, 256, 0, stream>>>(conv1_w, pi1_w, pi2_w, po1_w, po2_w, dw1_w, dw2_w,
                                          dw1_b, dw2_b,
                                          Bc1, Bpi1, Bpi2, Bpo1, Bpo2, dwT12, dwb12, Bpk);
    featPM_kernel<<<BB * TT * 400, 256, 0, stream>>>(feat, featPM);
    pool_kernel<<<BB * NSTEP * CC, 256, 0, stream>>>(feat, poolb);
    wd_kernel<<<BB * NSTEP, 64, 0, stream>>>(poolb, kc_w1, kc_g, kc_be, kc_mu, kc_var, kc_w2, kc_b2, wdT);
    copy_init_kernel<<<BB * CHW / 4 / 256, 256, 0, stream>>>(feat, out);

    for (int i = 0; i < NSTEP; i++) {
        int fx = NSTEP - 1 - i;   // 6..0
        const __bf16* src = (fx == NSTEP - 1) ? (featPM + (size_t)(TT - 1) * HWW * CC) : outPM;
        size_t bstr = (fx == NSTEP - 1) ? (size_t)TT * HWW * CC : (size_t)HWW * CC;
        dyndw_kernel<<<BB * HWW * 8 / 256, 256, 0, stream>>>(src, bstr, wdT, kc_bias, fpPM, fx);
        conv1_gemm<<<BB * 200, 256, 0, stream>>>(featPM, fpPM, Bc1, conv1_b, fusionPM, fx);
        pw1_gemm<<<BB * 800, 256, 0, stream>>>(fusionPM, Bpi1, Bpi2, pi1_b, pi2_b, u12PM);
        dwpw2_gemm<<<BB * 800, 256, 0, stream>>>(u12PM, dwT12, dwb12, Bpk, po1_b, po2_b, fusionPM, out, outPM, fx);
    }
}

// Round 11
// 962.635 us; speedup vs baseline: 1.3653x; 1.0215x over previous
//
#include <hip/hip_runtime.h>

typedef __attribute__((ext_vector_type(8))) __bf16 bf16x8;
typedef __attribute__((ext_vector_type(4))) float f32x4;
typedef __attribute__((ext_vector_type(2))) float f32x2;

#define BB 2
#define TT 8
#define CC 64
#define HH 160
#define WW 160
#define HWW 25600
#define RR 16
#define C2 128
#define C4 256
#define C8 512
#define NSTEP 7
#define CHW (CC*HWW)
#define EPSV 1e-5f

__device__ __forceinline__ f32x4 mfma16(bf16x8 a, bf16x8 b, f32x4 c) {
    return __builtin_amdgcn_mfma_f32_16x16x32_bf16(a, b, c, 0, 0, 0);
}

// unpack 2 bf16 (one dword) -> f32x2 and fma with packed weights (v_pk_fma_f32)
__device__ __forceinline__ void bpk_fma(unsigned d, f32x2 w, f32x2& a) {
    f32x2 u;
    u.x = __uint_as_float(d << 16);
    u.y = __uint_as_float(d & 0xffff0000u);
    a = __builtin_elementwise_fma(u, w, a);
}

// ---------------- pool: mean over H,W for frames 0..6 (fp32 planar input) ----------------
__global__ void pool_kernel(const float* __restrict__ feat, float* __restrict__ pool) {
    int idx = blockIdx.x;                 // b*NSTEP*CC + f*CC + c
    int b = idx / (NSTEP * CC);
    int f = (idx / CC) % NSTEP;
    int c = idx % CC;
    const float4* src = (const float4*)(feat + ((size_t)(b * TT + f) * CC + c) * HWW);
    float s = 0.f;
    for (int i = threadIdx.x; i < HWW / 4; i += 256) {
        float4 v = src[i];
        s += v.x + v.y + v.z + v.w;
    }
    __shared__ float sm[256];
    sm[threadIdx.x] = s;
    __syncthreads();
    for (int off = 128; off > 0; off >>= 1) {
        if (threadIdx.x < off) sm[threadIdx.x] += sm[threadIdx.x + off];
        __syncthreads();
    }
    if (threadIdx.x == 0) pool[idx] = sm[0] * (1.0f / HWW);
}

// ---------------- dynamic depthwise weights -> wdT[bf][t][c] (fp32) ----------------
__global__ void wd_kernel(const float* __restrict__ pool, const float* __restrict__ w1,
                          const float* __restrict__ gamma, const float* __restrict__ beta,
                          const float* __restrict__ mean, const float* __restrict__ var,
                          const float* __restrict__ w2, const float* __restrict__ b2,
                          float* __restrict__ wdT) {
    int bf = blockIdx.x;                  // 0..BB*NSTEP-1
    __shared__ float z[RR];
    int tid = threadIdx.x;                // 64 threads
    if (tid < RR) {
        const float* p = pool + bf * CC;
        float s = 0.f;
        for (int c = 0; c < CC; c++) s += p[c] * w1[tid * CC + c];
        s = (s - mean[tid]) * rsqrtf(var[tid] + EPSV) * gamma[tid] + beta[tid];
        z[tid] = s > 0.f ? s : 0.f;
    }
    __syncthreads();
    for (int o = tid; o < CC * 9; o += 64) {
        float s = b2[o];
        #pragma unroll
        for (int r = 0; r < RR; r++) s += z[r] * w2[o * RR + r];
        int c = o / 9, t = o % 9;
        wdT[bf * 576 + t * CC + c] = s;
    }
}

// ---------------- copy init slice (t=7) fp32 planar into output ----------------
__global__ void copy_init_kernel(const float* __restrict__ feat, float* __restrict__ out) {
    int i = blockIdx.x * 256 + threadIdx.x;   // over BB*CHW/4
    int n4 = CHW / 4;
    int b = i / n4;
    int r = i % n4;
    size_t off = ((size_t)(b * TT + (TT - 1)) * CHW) / 4 + r;
    ((float4*)out)[off] = ((const float4*)feat)[off];
}

// ---------------- prep weights: Bc1 [oc][t*128+ic] (round-5 layout) + dw/po packs ----------------
__global__ void prep_weights(const float* __restrict__ c1w,
                             const float* __restrict__ pi1, const float* __restrict__ pi2,
                             const float* __restrict__ po1, const float* __restrict__ po2,
                             const float* __restrict__ dw1, const float* __restrict__ dw2,
                             const float* __restrict__ dw1b, const float* __restrict__ dw2b,
                             __bf16* __restrict__ Bc1,
                             __bf16* __restrict__ Bpi1, __bf16* __restrict__ Bpi2,
                             __bf16* __restrict__ Bpo1, __bf16* __restrict__ Bpo2,
                             float* __restrict__ dwT12, float* __restrict__ dwb12,
                             __bf16* __restrict__ Bpk) {
    int idx = blockIdx.x * 256 + threadIdx.x;
    if (idx < 147456) {   // conv1: Bc1[oc][t*128+ic]
        int oc = idx / 1152, k = idx % 1152;
        int t = k >> 7, ic = k & 127;
        Bc1[idx] = (__bf16)c1w[(oc * 128 + ic) * 9 + t];
        return;
    }
    idx -= 147456;
    if (idx < 16384) { Bpi1[idx] = (__bf16)pi1[idx]; return; }
    idx -= 16384;
    if (idx < 16384) { Bpi2[idx] = (__bf16)pi2[idx]; return; }
    idx -= 16384;
    if (idx < 16384) { Bpo1[idx] = (__bf16)po1[idx]; return; }
    idx -= 16384;
    if (idx < 16384) { Bpo2[idx] = (__bf16)po2[idx]; return; }
    idx -= 16384;
    if (idx < 4608) {   // dwT12[t][c512]
        int t = idx / 512, c = idx % 512;
        dwT12[t * C8 + c] = (c < 256) ? dw1[c * 9 + t] : dw2[(c - 256) * 9 + t];
        return;
    }
    idx -= 4608;
    if (idx < 512) { dwb12[idx] = (idx < 256) ? dw1b[idx] : dw2b[idx - 256]; return; }
    idx -= 512;
    if (idx < 32768) {   // Bpk: po weights pre-packed in MFMA B-fragment order
        int j = idx & 7, ln = (idx >> 3) & 63, nt = (idx >> 9) & 3, kg = (idx >> 11) & 3, cc = idx >> 13;
        int lmx = ln & 15, lqx = ln >> 4;
        int oc = nt * 16 + lmx;
        int ci = (cc & 1) * 128 + kg * 32 + lqx * 8 + j;
        const float* src = (cc >> 1) ? po2 : po1;
        Bpk[idx] = (__bf16)src[oc * C4 + ci];
    }
}

// ---------------- feature planar fp32 -> pixel-major bf16 [bf][p][64] ----------------
__global__ void featPM_kernel(const float* __restrict__ feat, __bf16* __restrict__ featPM) {
    __shared__ float Lt[64 * 68];
    int bf = blockIdx.x / 400;            // b*TT+f, 0..15
    int p0 = (blockIdx.x % 400) * 64;
    int tid = threadIdx.x;
    int c = tid & 63, half = tid >> 6;
    const float* src = feat + ((size_t)bf * CC + c) * HWW + p0 + half * 16;
    #pragma unroll
    for (int k = 0; k < 16; k++) Lt[(half * 16 + k) * 68 + c] = src[k];
    __syncthreads();
    int cg = tid & 7;
    #pragma unroll
    for (int pass = 0; pass < 2; pass++) {
        int pl = (tid >> 3) + pass * 32;
        bf16x8 o;
        #pragma unroll
        for (int j = 0; j < 8; j++) o[j] = (__bf16)Lt[pl * 68 + cg * 8 + j];
        *(bf16x8*)(featPM + ((size_t)bf * HWW + p0 + pl) * CC + cg * 8) = o;
    }
}

// ---------------- dynamic depthwise conv: src (bf16 PM) -> fpPM (bf16 PM) ----------------
__global__ void dyndw_kernel(const __bf16* __restrict__ src, size_t bstr,
                             const float* __restrict__ wdT, const float* __restrict__ kc_bias,
                             __bf16* __restrict__ fpPM, int fx) {
    int gi = blockIdx.x * 256 + threadIdx.x;   // BB*HWW*8
    int c0 = (gi & 7) * 8;
    int rem = gi >> 3;
    int p = rem % HWW;
    int bb = rem / HWW;
    int py = p / WW, px = p % WW;
    float acc[8];
    float4 k0 = *(const float4*)(kc_bias + c0);
    float4 k1 = *(const float4*)(kc_bias + c0 + 4);
    acc[0]=k0.x; acc[1]=k0.y; acc[2]=k0.z; acc[3]=k0.w;
    acc[4]=k1.x; acc[5]=k1.y; acc[6]=k1.z; acc[7]=k1.w;
    const float* wb = wdT + (size_t)(bb * NSTEP + fx) * 576;
    const __bf16* sb = src + (size_t)bb * bstr;
    const int dyA[9] = {-1,-1,-1,0,0,0,1,1,1};
    const int dxA[9] = {-1,0,1,-1,0,1,-1,0,1};
    #pragma unroll
    for (int t = 0; t < 9; t++) {
        int dy = dyA[t], dx = dxA[t];
        if ((unsigned)(py + dy) < HH && (unsigned)(px + dx) < WW) {
            bf16x8 uv = *(const bf16x8*)(sb + (size_t)(p + dy * WW + dx) * CC + c0);
            float4 w0 = *(const float4*)(wb + t * CC + c0);
            float4 w1 = *(const float4*)(wb + t * CC + c0 + 4);
            acc[0] += (float)uv[0] * w0.x; acc[1] += (float)uv[1] * w0.y;
            acc[2] += (float)uv[2] * w0.z; acc[3] += (float)uv[3] * w0.w;
            acc[4] += (float)uv[4] * w1.x; acc[5] += (float)uv[5] * w1.y;
            acc[6] += (float)uv[6] * w1.z; acc[7] += (float)uv[7] * w1.w;
        }
    }
    bf16x8 o;
    #pragma unroll
    for (int j = 0; j < 8; j++) o[j] = (__bf16)acc[j];
    *(bf16x8*)(fpPM + ((size_t)bb * HWW + p) * CC + c0) = o;
}

// ---------------- conv1 implicit-GEMM: M=128px, N=128, K=1152, double-buffered 1-barrier pipeline ----------------
// grid BB*200 (XCD-swizzled). Per ks: load ks+1 (global) || MFMA buf[cur] || store buf[cur^1] -> 1 barrier.
__global__ void conv1_gemm(const __bf16* __restrict__ featPM, const __bf16* __restrict__ fpPM,
                           const __bf16* __restrict__ Bc1, const float* __restrict__ bias,
                           __bf16* __restrict__ fusionPM, int fx) {
    __shared__ __align__(16) __bf16 As[2][128 * 40];
    __shared__ __align__(16) __bf16 Bs[2][128 * 40];
    const int tid = threadIdx.x;
    const int bid = blockIdx.x;
    const int wg = (bid & 7) * 50 + (bid >> 3);   // bijective XCD swizzle (400 % 8 == 0)
    const int bb = wg / 200;
    const int p0 = (wg % 200) * 128;
    const int i = tid >> 1, h = tid & 1;
    const int p = p0 + i;
    const int py = p / WW, px = p % WW;
    const __bf16* featB = featPM + (size_t)(bb * TT + fx) * HWW * CC;
    const __bf16* fpB   = fpPM + (size_t)bb * HWW * CC;
    const int wv = tid >> 6, lane = tid & 63, lm = lane & 15, lq = lane >> 4;
    f32x4 acc[2][8];
    #pragma unroll
    for (int mt = 0; mt < 2; mt++)
        #pragma unroll
        for (int nt = 0; nt < 8; nt++) acc[mt][nt] = (f32x4){0.f, 0.f, 0.f, 0.f};

    uint4 a0, a1, w0q, w1q;
    // prologue: load + store ks=0 into buf 0
    {
        const bool valid = (py >= 1) && (px >= 1);   // ks=0: t=0 -> dy=-1, dx=-1
        a0 = (uint4){0,0,0,0}; a1 = (uint4){0,0,0,0};
        if (valid) {
            const __bf16* sp = featB + (size_t)(p - WW - 1) * CC;   // ci0=0
            a0 = *(const uint4*)(sp + h * 16);
            a1 = *(const uint4*)(sp + h * 16 + 8);
        }
        const __bf16* bp = Bc1 + (size_t)i * 1152 + h * 16;
        w0q = *(const uint4*)(bp);
        w1q = *(const uint4*)(bp + 8);
        *(uint4*)&As[0][i * 40 + h * 16]     = a0;
        *(uint4*)&As[0][i * 40 + h * 16 + 8] = a1;
        *(uint4*)&Bs[0][i * 40 + h * 16]     = w0q;
        *(uint4*)&Bs[0][i * 40 + h * 16 + 8] = w1q;
    }
    __syncthreads();

    for (int ks = 0; ks < 36; ks++) {
        const int cur = ks & 1;
        // issue next-ks global loads (hidden under MFMA)
        if (ks < 35) {
            const int kn = ks + 1;
            const int t = kn >> 2, ci0 = (kn & 3) * 32;
            const int dy = t / 3 - 1, dx = t % 3 - 1;
            const bool valid = ((unsigned)(py + dy) < HH) && ((unsigned)(px + dx) < WW);
            a0 = (uint4){0,0,0,0}; a1 = (uint4){0,0,0,0};
            if (valid) {
                const __bf16* sp = (ci0 < 64)
                    ? featB + (size_t)(p + dy * WW + dx) * CC + ci0
                    : fpB   + (size_t)(p + dy * WW + dx) * CC + (ci0 - 64);
                a0 = *(const uint4*)(sp + h * 16);
                a1 = *(const uint4*)(sp + h * 16 + 8);
            }
            const __bf16* bp = Bc1 + (size_t)i * 1152 + kn * 32 + h * 16;
            w0q = *(const uint4*)(bp);
            w1q = *(const uint4*)(bp + 8);
        }
        // MFMA on current buffer
        bf16x8 af0 = *(const bf16x8*)&As[cur][((wv * 2 + 0) * 16 + lm) * 40 + lq * 8];
        bf16x8 af1 = *(const bf16x8*)&As[cur][((wv * 2 + 1) * 16 + lm) * 40 + lq * 8];
        #pragma unroll
        for (int nt = 0; nt < 8; nt++) {
            bf16x8 bfr = *(const bf16x8*)&Bs[cur][(nt * 16 + lm) * 40 + lq * 8];
            acc[0][nt] = mfma16(af0, bfr, acc[0][nt]);
            acc[1][nt] = mfma16(af1, bfr, acc[1][nt]);
        }
        // store next-ks into other buffer
        if (ks < 35) {
            const int nb = cur ^ 1;
            *(uint4*)&As[nb][i * 40 + h * 16]     = a0;
            *(uint4*)&As[nb][i * 40 + h * 16 + 8] = a1;
            *(uint4*)&Bs[nb][i * 40 + h * 16]     = w0q;
            *(uint4*)&Bs[nb][i * 40 + h * 16 + 8] = w1q;
        }
        __syncthreads();
    }

    __bf16* ob = fusionPM + (size_t)bb * HWW * C2;
    #pragma unroll
    for (int mt = 0; mt < 2; mt++) {
        #pragma unroll
        for (int nt = 0; nt < 8; nt++) {
            const int oc = nt * 16 + lm;
            const float bs = bias[oc];
            #pragma unroll
            for (int r = 0; r < 4; r++) {
                const int pp = p0 + (wv * 2 + mt) * 16 + lq * 4 + r;
                float v = acc[mt][nt][r] + bs;
                v = v > 0.f ? v : 0.1f * v;
                ob[(size_t)pp * C2 + oc] = (__bf16)v;
            }
        }
    }
}

// ---------------- pw1 fused both branches: u12 = fusion_half @ pi^T + b (bf16 out) ----------------
// grid: BB * 200 * 4  (nb: branch = nb>>1, sub-half = nb&1)
__global__ void pw1_gemm(const __bf16* __restrict__ fusionPM,
                         const __bf16* __restrict__ Bpi1, const __bf16* __restrict__ Bpi2,
                         const float* __restrict__ pi1b, const float* __restrict__ pi2b,
                         __bf16* __restrict__ u12PM) {
    __shared__ __align__(16) __bf16 As[128 * 40];
    __shared__ __align__(16) __bf16 Bs[128 * 40];
    const int tid = threadIdx.x;
    const int bb = blockIdx.x / 800;
    const int rem = blockIdx.x % 800;
    const int p0 = (rem >> 2) * 128;
    const int nb = rem & 3;
    const int br = nb >> 1, ns = nb & 1;
    const __bf16* Bpi = br ? Bpi2 : Bpi1;
    const float* bias = br ? pi2b : pi1b;
    const int i = tid >> 1, h = tid & 1;
    const int p = p0 + i;
    const __bf16* fB = fusionPM + (size_t)bb * HWW * C2 + br * CC;
    const int wv = tid >> 6, lane = tid & 63, lm = lane & 15, lq = lane >> 4;
    f32x4 acc[2][8];
    #pragma unroll
    for (int mt = 0; mt < 2; mt++)
        #pragma unroll
        for (int nt = 0; nt < 8; nt++) acc[mt][nt] = (f32x4){0.f, 0.f, 0.f, 0.f};

    #pragma unroll
    for (int ks = 0; ks < 2; ks++) {
        const int ci0 = ks * 32;
        const __bf16* sp = fB + (size_t)p * C2 + ci0 + h * 16;
        uint4 a0 = *(const uint4*)(sp);
        uint4 a1 = *(const uint4*)(sp + 8);
        const __bf16* bp = Bpi + (size_t)(ns * 128 + i) * 64 + ci0 + h * 16;
        uint4 w0q = *(const uint4*)(bp);
        uint4 w1q = *(const uint4*)(bp + 8);
        __syncthreads();
        *(uint4*)&As[i * 40 + h * 16]     = a0;
        *(uint4*)&As[i * 40 + h * 16 + 8] = a1;
        *(uint4*)&Bs[i * 40 + h * 16]     = w0q;
        *(uint4*)&Bs[i * 40 + h * 16 + 8] = w1q;
        __syncthreads();
        bf16x8 af0 = *(const bf16x8*)&As[((wv * 2 + 0) * 16 + lm) * 40 + lq * 8];
        bf16x8 af1 = *(const bf16x8*)&As[((wv * 2 + 1) * 16 + lm) * 40 + lq * 8];
        #pragma unroll
        for (int nt = 0; nt < 8; nt++) {
            bf16x8 bf = *(const bf16x8*)&Bs[(nt * 16 + lm) * 40 + lq * 8];
            acc[0][nt] = mfma16(af0, bf, acc[0][nt]);
            acc[1][nt] = mfma16(af1, bf, acc[1][nt]);
        }
    }
    __bf16* ub = u12PM + (size_t)bb * HWW * C8;
    #pragma unroll
    for (int mt = 0; mt < 2; mt++) {
        #pragma unroll
        for (int nt = 0; nt < 8; nt++) {
            const int ocl = ns * 128 + nt * 16 + lm;      // within branch's 256
            const int oc = br * 256 + ocl;                // within 512
            const float bs = bias[ocl];
            #pragma unroll
            for (int r = 0; r < 4; r++) {
                const int pp = p0 + (wv * 2 + mt) * 16 + lq * 4 + r;
                ub[(size_t)pp * C8 + oc] = (__bf16)(acc[mt][nt][r] + bs);
            }
        }
    }
}

// ---------------- fused dw3x3 + pw2 + gate epilogue, 32-px tiles, LDS-staged u, async-stage ----------------
// grid BB*800 (XCD-swizzled). Per chunk: prefetch next chunk's u into REGS before dw-compute
// (latency hides under dw+MFMA), commit regs->uL after bar1 (all uL reads of current chunk done).
__global__ void dwpw2_gemm(const __bf16* __restrict__ u12PM,
                           const float* __restrict__ dwT12, const float* __restrict__ dwb12,
                           const __bf16* __restrict__ Bpk,
                           const float* __restrict__ pob1, const float* __restrict__ pob2,
                           const __bf16* __restrict__ fusionPM,
                           float* __restrict__ out, __bf16* __restrict__ outPM, int fx) {
    __shared__ __align__(16) __bf16 uL[3 * 34 * 128];   // 26112 B
    __shared__ __align__(16) __bf16 Vt[32 * 136];       //  8704 B
    const int tid = threadIdx.x;
    const int bid = blockIdx.x;
    const int wg = (bid & 7) * 200 + (bid >> 3);        // bijective XCD swizzle (1600 % 8 == 0)
    const int bb = wg / 800;
    const int p0 = (wg % 800) * 32;                     // strip: 32 px within one image row
    const int py = p0 / WW, px0 = p0 % WW;
    const __bf16* uB = u12PM + (size_t)bb * HWW * C8;
    const int wv = tid >> 6, lane = tid & 63, lm = lane & 15, lq = lane >> 4;
    const int mt = wv & 1, nh = wv >> 1;
    const int cg = tid & 15, prow = tid >> 4;           // ch-group 0..15, px 0..15 (+16)

    f32x4 acc[2][2];   // [branch][ntl]
    #pragma unroll
    for (int b = 0; b < 2; b++)
        #pragma unroll
        for (int n = 0; n < 2; n++) acc[b][n] = (f32x4){0.f, 0.f, 0.f, 0.f};

    const int rbase = py - 1, cbase = px0 - 1;

    // per-thread staging addresses (it in 0..6; idx = it*256+tid < 1632)
    uint4 pre[7];
    auto load_chunk = [&](int cc) {
        const int c0ch = cc * 128;
        #pragma unroll
        for (int it = 0; it < 7; it++) {
            int idx = it * 256 + tid;
            uint4 v = {0,0,0,0};
            if (idx < 1632) {
                int s = idx >> 4, part = idx & 15;
                int r = s / 34, c = s - r * 34;
                int gr = rbase + r, gc = cbase + c;
                if ((unsigned)gr < HH && (unsigned)gc < WW)
                    v = *(const uint4*)(uB + (size_t)(gr * WW + gc) * C8 + c0ch + part * 8);
            }
            pre[it] = v;
        }
    };
    auto store_chunk = [&]() {
        #pragma unroll
        for (int it = 0; it < 7; it++) {
            int idx = it * 256 + tid;
            if (idx < 1632) *(uint4*)&uL[idx * 8] = pre[it];
        }
    };

    load_chunk(0);
    store_chunk();
    __syncthreads();

    #pragma unroll
    for (int cc = 0; cc < 4; cc++) {
        // issue next chunk's global loads early (latency hides under dw + MFMA)
        if (cc < 3) load_chunk(cc + 1);

        // ---- dw 3x3: guard-free, packed fma (reads uL) ----
        const int c0 = cc * 128 + cg * 8;
        f32x2 a0[4], a1[4];
        {
            float4 b0 = *(const float4*)(dwb12 + c0);
            float4 b1 = *(const float4*)(dwb12 + c0 + 4);
            a0[0] = (f32x2){b0.x, b0.y}; a0[1] = (f32x2){b0.z, b0.w};
            a0[2] = (f32x2){b1.x, b1.y}; a0[3] = (f32x2){b1.z, b1.w};
            #pragma unroll
            for (int k = 0; k < 4; k++) a1[k] = a0[k];
        }
        #pragma unroll
        for (int t = 0; t < 9; t++) {
            const int dy = t / 3 - 1, dx = t % 3 - 1;
            float4 w0 = *(const float4*)(dwT12 + t * C8 + c0);
            float4 w1 = *(const float4*)(dwT12 + t * C8 + c0 + 4);
            f32x2 wp[4] = {(f32x2){w0.x, w0.y}, (f32x2){w0.z, w0.w},
                           (f32x2){w1.x, w1.y}, (f32x2){w1.z, w1.w}};
            const int base = ((1 + dy) * 34 + 1 + dx) * 128 + cg * 8;
            uint4 ua = *(const uint4*)&uL[base + prow * 128];
            uint4 ub4 = *(const uint4*)&uL[base + (prow + 16) * 128];
            bpk_fma(ua.x, wp[0], a0[0]); bpk_fma(ua.y, wp[1], a0[1]);
            bpk_fma(ua.z, wp[2], a0[2]); bpk_fma(ua.w, wp[3], a0[3]);
            bpk_fma(ub4.x, wp[0], a1[0]); bpk_fma(ub4.y, wp[1], a1[1]);
            bpk_fma(ub4.z, wp[2], a1[2]); bpk_fma(ub4.w, wp[3], a1[3]);
        }
        bf16x8 o0, o1;
        #pragma unroll
        for (int k = 0; k < 4; k++) {
            o0[2 * k] = (__bf16)a0[k].x; o0[2 * k + 1] = (__bf16)a0[k].y;
            o1[2 * k] = (__bf16)a1[k].x; o1[2 * k + 1] = (__bf16)a1[k].y;
        }
        *(bf16x8*)&Vt[prow * 136 + cg * 8]        = o0;
        *(bf16x8*)&Vt[(16 + prow) * 136 + cg * 8] = o1;
        __syncthreads();   // bar1: Vt ready; all uL reads of this chunk complete

        // ---- MFMA for this chunk's branch (reads Vt, not uL) ----
        const int br = cc >> 1;
        const __bf16* bbase = Bpk + cc * 8192 + (size_t)lane * 8;
        #pragma unroll
        for (int kg = 0; kg < 4; kg++) {
            bf16x8 af = *(const bf16x8*)&Vt[(mt * 16 + lm) * 136 + kg * 32 + lq * 8];
            #pragma unroll
            for (int ntl = 0; ntl < 2; ntl++) {
                bf16x8 bfr = *(const bf16x8*)(bbase + kg * 2048 + (nh * 2 + ntl) * 512);
                acc[br][ntl] = mfma16(af, bfr, acc[br][ntl]);
            }
        }

        // commit prefetched chunk to uL (safe: uL reads done before bar1; MFMA reads Vt only)
        if (cc < 3) {
            store_chunk();
            __syncthreads();   // bar2: uL writes + Vt reads ordered before next chunk
        }
    }
    // ---- epilogue: gate + combine ----
    const __bf16* fB = fusionPM + (size_t)bb * HWW * C2;
    __bf16* opB = outPM + (size_t)bb * HWW * CC;
    float* outp = out + (size_t)(bb * TT + fx) * CC * HWW;
    const int ppb = p0 + mt * 16 + lq * 4;
    #pragma unroll
    for (int ntl = 0; ntl < 2; ntl++) {
        const int oc = (nh * 2 + ntl) * 16 + lm;
        const float bs1 = pob1[oc];
        const float bs2 = pob2[oc];
        float4 vo;
        #pragma unroll
        for (int r = 0; r < 4; r++) {
            const int pp = ppb + r;
            float g1 = 1.f / (1.f + __expf(-(acc[0][ntl][r] + bs1)));
            float g2 = 1.f / (1.f + __expf(-(acc[1][ntl][r] + bs2)));
            float f1 = (float)fB[(size_t)pp * C2 + oc];
            float f2 = (float)fB[(size_t)pp * C2 + CC + oc];
            float val = f1 * g1 + f2 * g2;
            (&vo.x)[r] = val;
            opB[(size_t)pp * CC + oc] = (__bf16)val;
        }
        *(float4*)(outp + (size_t)oc * HWW + ppb) = vo;
    }
}

extern "C" void kernel_launch(void* const* d_in, const int* in_sizes, int n_in,
                              void* d_out, int out_size, void* d_ws, size_t ws_size,
                              hipStream_t stream) {
    const float* feat     = (const float*)d_in[0];
    const float* kc_w1    = (const float*)d_in[1];
    const float* kc_g     = (const float*)d_in[2];
    const float* kc_be    = (const float*)d_in[3];
    const float* kc_mu    = (const float*)d_in[4];
    const float* kc_var   = (const float*)d_in[5];
    const float* kc_w2    = (const float*)d_in[6];
    const float* kc_b2    = (const float*)d_in[7];
    const float* kc_bias  = (const float*)d_in[8];
    const float* conv1_w  = (const float*)d_in[9];
    const float* conv1_b  = (const float*)d_in[10];
    const float* pi1_w    = (const float*)d_in[11];
    const float* pi1_b    = (const float*)d_in[12];
    const float* dw1_w    = (const float*)d_in[13];
    const float* dw1_b    = (const float*)d_in[14];
    const float* po1_w    = (const float*)d_in[15];
    const float* po1_b    = (const float*)d_in[16];
    const float* pi2_w    = (const float*)d_in[17];
    const float* pi2_b    = (const float*)d_in[18];
    const float* dw2_w    = (const float*)d_in[19];
    const float* dw2_b    = (const float*)d_in[20];
    const float* po2_w    = (const float*)d_in[21];
    const float* po2_b    = (const float*)d_in[22];
    float* out = (float*)d_out;

    char* W = (char*)d_ws;
    __bf16* featPM   = (__bf16*)W; W += (size_t)BB * TT * HWW * CC * 2;   // 52.4 MB
    __bf16* fpPM     = (__bf16*)W; W += (size_t)BB * HWW * CC * 2;        //  6.6 MB
    __bf16* fusionPM = (__bf16*)W; W += (size_t)BB * HWW * C2 * 2;        // 13.1 MB
    __bf16* u12PM    = (__bf16*)W; W += (size_t)BB * HWW * C8 * 2;        // 52.4 MB (bf16)
    __bf16* outPM    = (__bf16*)W; W += (size_t)BB * HWW * CC * 2;        //  6.6 MB
    __bf16* Bc1      = (__bf16*)W; W += 294912;
    __bf16* Bpi1     = (__bf16*)W; W += 32768;
    __bf16* Bpi2     = (__bf16*)W; W += 32768;
    __bf16* Bpo1     = (__bf16*)W; W += 32768;
    __bf16* Bpo2     = (__bf16*)W; W += 32768;
    __bf16* Bpk      = (__bf16*)W; W += 65536;
    float*  dwT12    = (float*)W;  W += 18432;
    float*  dwb12    = (float*)W;  W += 2048;
    float*  poolb    = (float*)W;  W += 4096;
    float*  wdT      = (float*)W;  W += 32256;

    prep_weights<<<980, 256, 0, stream>>>(conv1_w, pi1_w, pi2_w, po1_w, po2_w, dw1_w, dw2_w,
                                          dw1_b, dw2_b,
                                          Bc1, Bpi1, Bpi2, Bpo1, Bpo2, dwT12, dwb12, Bpk);
    featPM_kernel<<<BB * TT * 400, 256, 0, stream>>>(feat, featPM);
    pool_kernel<<<BB * NSTEP * CC, 256, 0, stream>>>(feat, poolb);
    wd_kernel<<<BB * NSTEP, 64, 0, stream>>>(poolb, kc_w1, kc_g, kc_be, kc_mu, kc_var, kc_w2, kc_b2, wdT);
    copy_init_kernel<<<BB * CHW / 4 / 256, 256, 0, stream>>>(feat, out);

    for (int i = 0; i < NSTEP; i++) {
        int fx = NSTEP - 1 - i;   // 6..0
        const __bf16* src = (fx == NSTEP - 1) ? (featPM + (size_t)(TT - 1) * HWW * CC) : outPM;
        size_t bstr = (fx == NSTEP - 1) ? (size_t)TT * HWW * CC : (size_t)HWW * CC;
        dyndw_kernel<<<BB * HWW * 8 / 256, 256, 0, stream>>>(src, bstr, wdT, kc_bias, fpPM, fx);
        conv1_gemm<<<BB * 200, 256, 0, stream>>>(featPM, fpPM, Bc1, conv1_b, fusionPM, fx);
        pw1_gemm<<<BB * 800, 256, 0, stream>>>(fusionPM, Bpi1, Bpi2, pi1_b, pi2_b, u12PM);
        dwpw2_gemm<<<BB * 800, 256, 0, stream>>>(u12PM, dwT12, dwb12, Bpk, po1_b, po2_b, fusionPM, out, outPM, fx);
    }
}